// Round 8
// baseline (501.070 us; speedup 1.0000x reference)
//
#include <hip/hip_runtime.h>
#include <hip/hip_bf16.h>

// NodeModel: edge MLP ([x[col]||edge_attr] -> 64 relu -> 64 relu) -> scatter_mean
// over row -> node MLP ([x||agg||u[batch]] -> 64 relu -> 32).
// N=50000, E=1.6M, D_H=64.
//
// R8: R5 edge kernel (R6's reg-pipeline reverted: it raised FETCH 186->281MB
// and dur 190->240us) + LDS OVERLAY: In (2KB), H2 (2KB), D2 (4.25KB) are
// temporally disjoint per wave -> one 4352B/wave scratch. LDS/block 33->17KB,
// __launch_bounds__(256,5) -> ~20 waves/CU (was ~12). Latency-bound kernel,
// occupancy is the lever. Grid = 1280 (5 blocks/CU resident), grid-stride.

typedef __attribute__((ext_vector_type(8))) short bf16x8;
typedef __attribute__((ext_vector_type(4))) float f32x4;

__device__ __forceinline__ unsigned short f2bf(float f) {
    union { float f; unsigned u; } v; v.f = f;
    return (unsigned short)((v.u + 0x7FFFu + ((v.u >> 16) & 1u)) >> 16);
}

// ---------------- counting sort ----------------

__global__ __launch_bounds__(256) void count_rows(
    const int* __restrict__ erow, int* __restrict__ counts, int E)
{
    const int gid = blockIdx.x * blockDim.x + threadIdx.x;
    const int stride = gridDim.x * blockDim.x;
    const int n4 = E >> 2;
    for (int i = gid; i < n4; i += stride) {
        const int4 r = ((const int4*)erow)[i];
        atomicAdd(&counts[r.x], 1);
        atomicAdd(&counts[r.y], 1);
        atomicAdd(&counts[r.z], 1);
        atomicAdd(&counts[r.w], 1);
    }
    for (int i = (n4 << 2) + gid; i < E; i += stride)
        atomicAdd(&counts[erow[i]], 1);
}

__global__ __launch_bounds__(256) void scan_blocks(
    const int* __restrict__ counts, int* __restrict__ excl,
    int* __restrict__ bsum, int N)
{
    __shared__ int tmp[256];
    const int t = threadIdx.x;
    const int i = blockIdx.x * 256 + t;
    const int v = (i < N) ? counts[i] : 0;
    tmp[t] = v; __syncthreads();
#pragma unroll
    for (int o = 1; o < 256; o <<= 1) {
        const int a = (t >= o) ? tmp[t - o] : 0;
        __syncthreads();
        tmp[t] += a;
        __syncthreads();
    }
    if (i < N) excl[i] = tmp[t] - v;
    if (t == 255) bsum[blockIdx.x] = tmp[t];
}

__global__ __launch_bounds__(256) void scan_bsum(int* __restrict__ bsum, int nb)
{
    __shared__ int tmp[256];
    const int t = threadIdx.x;
    const int v = (t < nb) ? bsum[t] : 0;
    tmp[t] = v; __syncthreads();
#pragma unroll
    for (int o = 1; o < 256; o <<= 1) {
        const int a = (t >= o) ? tmp[t - o] : 0;
        __syncthreads();
        tmp[t] += a;
        __syncthreads();
    }
    if (t < nb) bsum[t] = tmp[t] - v;   // exclusive
}

__global__ __launch_bounds__(256) void scan_add(
    int* __restrict__ rowstart, const int* __restrict__ bsum, int N, int E)
{
    const int i = blockIdx.x * 256 + threadIdx.x;
    if (i < N) rowstart[i] += bsum[blockIdx.x];
    if (i == 0) rowstart[N] = E;
}

// sorted4[pos] = {edge_id, col, row, 0}
__global__ __launch_bounds__(256) void permute_edges(
    const int* __restrict__ erow, const int* __restrict__ ecol,
    int* __restrict__ cursor, int4* __restrict__ sorted4, int E)
{
    const int gid = blockIdx.x * blockDim.x + threadIdx.x;
    const int stride = gridDim.x * blockDim.x;
    const int n4 = E >> 2;
    for (int i = gid; i < n4; i += stride) {
        const int4 r = ((const int4*)erow)[i];
        const int4 c = ((const int4*)ecol)[i];
        const int e0 = i << 2;
        int pos;
        pos = atomicAdd(&cursor[r.x], 1); sorted4[pos] = int4{e0,     c.x, r.x, 0};
        pos = atomicAdd(&cursor[r.y], 1); sorted4[pos] = int4{e0 + 1, c.y, r.y, 0};
        pos = atomicAdd(&cursor[r.z], 1); sorted4[pos] = int4{e0 + 2, c.z, r.z, 0};
        pos = atomicAdd(&cursor[r.w], 1); sorted4[pos] = int4{e0 + 3, c.w, r.w, 0};
    }
    for (int i = (n4 << 2) + gid; i < E; i += stride) {
        const int r = erow[i];
        const int pos = atomicAdd(&cursor[r], 1);
        sorted4[pos] = int4{i, ecol[i], r, 0};
    }
}

// ---------------- edge MLP (sorted) + segment-reduced scatter ----------------

#define D2S 68                 // D2 row stride (floats); breaks store conflicts
#define WV_SCR (D2S * 16 * 4)  // 4352 B per-wave scratch (In/H2/D2 overlaid)

__global__ __launch_bounds__(256, 5) void edge_mlp_mfma(
    const float* __restrict__ x,        // [N,32]
    const int4*  __restrict__ sorted4,  // [E] {eid,col,row,0}
    const float* __restrict__ eattr,    // [E,32]
    const float* __restrict__ W1a,      // [64,64] (in,out)
    const float* __restrict__ b1a,      // [64]
    const float* __restrict__ W1b,      // [64,64]
    const float* __restrict__ b1b,      // [64]
    float* __restrict__ summed,         // [N,64]
    int E)
{
    // One scratch; per-wave 4352B region is reused in 3 phases per tile:
    //   phase A: In  bf16[16][64] @ bytes [0,2048)
    //   phase B: H2  bf16[16][64] @ bytes [2048,4096)
    //   phase C: D2  f32 [16][68] @ bytes [0,4352)   (overlaps A and B)
    // Phases are sequential within the wave (LDS pipe is in-order per wave;
    // compiler sees one array -> keeps DS ordering via lgkmcnt).
    __shared__ __align__(16) char SCR[4 * WV_SCR];

    const int tid  = threadIdx.x;
    const int lane = tid & 63;
    const int wv   = tid >> 6;
    const int g    = lane >> 4;
    const int el   = lane & 15;

    char* const wbase = SCR + wv * WV_SCR;
    unsigned short* const inw = (unsigned short*)wbase;           // [16][64]
    unsigned short* const h2w = (unsigned short*)(wbase + 2048);  // [16][64]
    float*          const d2w = (float*)wbase;                    // [16][68]

    // persistent weight fragments: A row = lane&15, k = 8*(lane>>4)+j;
    // B col = lane&15, same k (identical mappings)
    bf16x8 wa[4][2], wb[4][2];
    f32x4  bias1[4];
    float  bias2s[4];
#pragma unroll
    for (int mt = 0; mt < 4; ++mt) {
        const int o = mt * 16 + el;
#pragma unroll
        for (int ks = 0; ks < 2; ++ks) {
            bf16x8 ta, tb;
#pragma unroll
            for (int j = 0; j < 8; ++j) {
                const int k = ks * 32 + 8 * g + j;
                ta[j] = (short)f2bf(W1a[k * 64 + o]);
                tb[j] = (short)f2bf(W1b[k * 64 + o]);
            }
            wa[mt][ks] = ta;
            wb[mt][ks] = tb;
        }
#pragma unroll
        for (int r = 0; r < 4; ++r) bias1[mt][r] = b1a[mt * 16 + 4 * g + r];
        bias2s[mt] = b1b[o];
    }

    const int ntile = (E + 15) >> 4;
    const int wid   = blockIdx.x * 4 + wv;
    const int nw    = gridDim.x * 4;

    for (int t = wid; t < ntile; t += nw) {
        const int ebase = t << 4;

        // ---- stage 16 sorted edges: 4 lanes/edge -> bf16 -> swizzled LDS ----
        {
            const int le  = lane >> 2;
            const int p   = lane & 3;
            const int pos = ebase + le;
            float4 v[4];
            if (pos < E) {
                const int4 s4 = sorted4[pos];
                const float* src;
                if (p < 2) src = x + (size_t)s4.y * 32 + p * 16;
                else       src = eattr + (size_t)s4.x * 32 + (p - 2) * 16;
#pragma unroll
                for (int q = 0; q < 4; ++q) v[q] = ((const float4*)src)[q];
            } else {
#pragma unroll
                for (int q = 0; q < 4; ++q) v[q] = float4{0.f, 0.f, 0.f, 0.f};
            }
            bf16x8 c0, c1;
#pragma unroll
            for (int q = 0; q < 2; ++q) {
                c0[4*q+0] = (short)f2bf(v[q].x);   c0[4*q+1] = (short)f2bf(v[q].y);
                c0[4*q+2] = (short)f2bf(v[q].z);   c0[4*q+3] = (short)f2bf(v[q].w);
                c1[4*q+0] = (short)f2bf(v[q+2].x); c1[4*q+1] = (short)f2bf(v[q+2].y);
                c1[4*q+2] = (short)f2bf(v[q+2].z); c1[4*q+3] = (short)f2bf(v[q+2].w);
            }
            const int sw = le & 7;
            unsigned short* row = inw + le * 64;
            *(bf16x8*)(row + (((2 * p)     ^ sw) * 8)) = c0;
            *(bf16x8*)(row + (((2 * p + 1) ^ sw) * 8)) = c1;
        }
        // wave-private LDS: in-order DS pipe + compiler lgkmcnt, no barrier

        const int sw = el & 7;

        // ---- layer 1: D1 = W1a^T (A) x In^T (B) -> neuron-major ----
        const unsigned short* brow = inw + el * 64;
        const bf16x8 bf0 = *(const bf16x8*)(brow + (((0 + g) ^ sw) * 8));
        const bf16x8 bf1 = *(const bf16x8*)(brow + (((4 + g) ^ sw) * 8));
        f32x4 a0 = bias1[0], a1 = bias1[1], a2 = bias1[2], a3 = bias1[3];
        a0 = __builtin_amdgcn_mfma_f32_16x16x32_bf16(wa[0][0], bf0, a0, 0, 0, 0);
        a1 = __builtin_amdgcn_mfma_f32_16x16x32_bf16(wa[1][0], bf0, a1, 0, 0, 0);
        a2 = __builtin_amdgcn_mfma_f32_16x16x32_bf16(wa[2][0], bf0, a2, 0, 0, 0);
        a3 = __builtin_amdgcn_mfma_f32_16x16x32_bf16(wa[3][0], bf0, a3, 0, 0, 0);
        a0 = __builtin_amdgcn_mfma_f32_16x16x32_bf16(wa[0][1], bf1, a0, 0, 0, 0);
        a1 = __builtin_amdgcn_mfma_f32_16x16x32_bf16(wa[1][1], bf1, a1, 0, 0, 0);
        a2 = __builtin_amdgcn_mfma_f32_16x16x32_bf16(wa[2][1], bf1, a2, 0, 0, 0);
        a3 = __builtin_amdgcn_mfma_f32_16x16x32_bf16(wa[3][1], bf1, a3, 0, 0, 0);

        // ---- relu -> bf16 -> H2 (wave-private, swizzled) ----
        unsigned short* hrow = h2w + el * 64;
        {
            f32x4 accs[4] = {a0, a1, a2, a3};
#pragma unroll
            for (int mt = 0; mt < 4; ++mt) {
                unsigned short pk[4];
#pragma unroll
                for (int r = 0; r < 4; ++r) pk[r] = f2bf(fmaxf(accs[mt][r], 0.f));
                const int hid   = mt * 16 + 4 * g;
                const int chunk = hid >> 3;
                const int off   = hid & 7;
                *(uint2*)(hrow + ((chunk ^ sw) * 8 + off)) = *(uint2*)pk;
            }
        }

        // ---- layer 2, operand-swapped: D2 = H1 (A) x W1b (B) -> EDGE-major ----
        const bf16x8 hb0 = *(const bf16x8*)(hrow + (((0 + g) ^ sw) * 8));
        const bf16x8 hb1 = *(const bf16x8*)(hrow + (((4 + g) ^ sw) * 8));
        f32x4 d0 = {bias2s[0], bias2s[0], bias2s[0], bias2s[0]};
        f32x4 d1 = {bias2s[1], bias2s[1], bias2s[1], bias2s[1]};
        f32x4 d2 = {bias2s[2], bias2s[2], bias2s[2], bias2s[2]};
        f32x4 d3 = {bias2s[3], bias2s[3], bias2s[3], bias2s[3]};
        d0 = __builtin_amdgcn_mfma_f32_16x16x32_bf16(hb0, wb[0][0], d0, 0, 0, 0);
        d1 = __builtin_amdgcn_mfma_f32_16x16x32_bf16(hb0, wb[1][0], d1, 0, 0, 0);
        d2 = __builtin_amdgcn_mfma_f32_16x16x32_bf16(hb0, wb[2][0], d2, 0, 0, 0);
        d3 = __builtin_amdgcn_mfma_f32_16x16x32_bf16(hb0, wb[3][0], d3, 0, 0, 0);
        d0 = __builtin_amdgcn_mfma_f32_16x16x32_bf16(hb1, wb[0][1], d0, 0, 0, 0);
        d1 = __builtin_amdgcn_mfma_f32_16x16x32_bf16(hb1, wb[1][1], d1, 0, 0, 0);
        d2 = __builtin_amdgcn_mfma_f32_16x16x32_bf16(hb1, wb[2][1], d2, 0, 0, 0);
        d3 = __builtin_amdgcn_mfma_f32_16x16x32_bf16(hb1, wb[3][1], d3, 0, 0, 0);

        // ---- relu -> D2 f32[16][68] (overlays In+H2; phase-ordered) ----
        {
            f32x4 dd[4] = {d0, d1, d2, d3};
#pragma unroll
            for (int nt = 0; nt < 4; ++nt)
#pragma unroll
                for (int r = 0; r < 4; ++r) {
                    const int eg = ebase + 4 * g + r;
                    d2w[(4 * g + r) * D2S + nt * 16 + el] =
                        (eg < E) ? fmaxf(dd[nt][r], 0.f) : 0.f;
                }
        }

        // ---- segment flush: rows are sorted runs; lane = neuron ----
        const int myrow = (ebase + el < E) ? sorted4[ebase + el].z : -1;
        float acc = 0.f;
        int prev = __shfl(myrow, 0);
#pragma unroll
        for (int j = 0; j < 16; ++j) {
            const float v = d2w[j * D2S + lane];
            const int rj = __shfl(myrow, j);
            if (rj != prev) {                        // wave-uniform branch
                if (prev >= 0)
                    unsafeAtomicAdd(&summed[(size_t)prev * 64 + lane], acc);
                acc = 0.f;
                prev = rj;
            }
            acc += v;
        }
        if (prev >= 0)
            unsafeAtomicAdd(&summed[(size_t)prev * 64 + lane], acc);
    }
}

// ---------------- node MLP via MFMA ----------------

__global__ __launch_bounds__(256, 2) void node_mlp_mfma(
    const float* __restrict__ x,        // [N,32]
    const float* __restrict__ summed,   // [N,64]
    const int*   __restrict__ rowstart, // [N+1]
    const float* __restrict__ u,        // [G,16]
    const int*   __restrict__ batch,    // [N]
    const float* __restrict__ W2a,      // [112,64]
    const float* __restrict__ b2a,      // [64]
    const float* __restrict__ W2b,      // [64,32]
    const float* __restrict__ b2b,      // [32]
    float* __restrict__ out,            // [N,32]
    int N)
{
    __shared__ __align__(16) unsigned short In[64 * 128];  // 16KB
    __shared__ __align__(16) unsigned short H[64 * 64];    // 8KB

    const int tid  = threadIdx.x;
    const int lane = tid & 63;
    const int wv   = tid >> 6;
    const int g    = lane >> 4;
    const int el   = lane & 15;

    bf16x8 wa[4][4];
    f32x4  bias1[4];
#pragma unroll
    for (int mt = 0; mt < 4; ++mt) {
        const int o = mt * 16 + el;
#pragma unroll
        for (int ks = 0; ks < 4; ++ks) {
            bf16x8 ta;
#pragma unroll
            for (int j = 0; j < 8; ++j) {
                const int k = ks * 32 + 8 * g + j;
                ta[j] = (k < 112) ? (short)f2bf(W2a[k * 64 + o]) : (short)0;
            }
            wa[mt][ks] = ta;
        }
#pragma unroll
        for (int r = 0; r < 4; ++r) bias1[mt][r] = b2a[mt * 16 + 4 * g + r];
    }
    bf16x8 wb[2][2];
    float  bias2s[2];
#pragma unroll
    for (int nt = 0; nt < 2; ++nt) {
        const int o = nt * 16 + el;
#pragma unroll
        for (int ks = 0; ks < 2; ++ks) {
            bf16x8 tb;
#pragma unroll
            for (int j = 0; j < 8; ++j) {
                const int k = ks * 32 + 8 * g + j;
                tb[j] = (short)f2bf(W2b[k * 32 + o]);
            }
            wb[nt][ks] = tb;
        }
        bias2s[nt] = b2b[o];
    }

    unsigned short* const inrow = In + (wv * 16) * 128;
    unsigned short* const hrow0 = H + (wv * 16) * 64;

    const int ntile = (N + 15) >> 4;
    const int wid   = blockIdx.x * 4 + wv;
    const int nw    = gridDim.x * 4;

    for (int t = wid; t < ntile; t += nw) {
        const int nbase = t << 4;

        // ---- stage 16 nodes: 4 lanes/node, 32-float segment each ----
        // row layout (128 bf16): [x(32) | agg(32) | agg(32) | u(16)+0(16)]
        {
            const int le = lane >> 2;
            const int p  = lane & 3;
            const int n  = nbase + le;
            float4 v[8];
            if (n < N) {
                if (p == 0) {
                    const float4* xp = (const float4*)(x + (size_t)n * 32);
#pragma unroll
                    for (int q = 0; q < 8; ++q) v[q] = xp[q];
                } else if (p < 3) {
                    const int cnt = rowstart[n + 1] - rowstart[n];
                    const float inv = 1.0f / fmaxf((float)cnt, 1.0f);
                    const float4* sp = (const float4*)(summed + (size_t)n * 64 + (p - 1) * 32);
#pragma unroll
                    for (int q = 0; q < 8; ++q) {
                        v[q] = sp[q];
                        v[q].x *= inv; v[q].y *= inv; v[q].z *= inv; v[q].w *= inv;
                    }
                } else {
                    const int gb = batch[n];
                    const float4* up = (const float4*)(u + (size_t)gb * 16);
#pragma unroll
                    for (int q = 0; q < 4; ++q) v[q] = up[q];
#pragma unroll
                    for (int q = 4; q < 8; ++q) v[q] = float4{0.f, 0.f, 0.f, 0.f};
                }
            } else {
#pragma unroll
                for (int q = 0; q < 8; ++q) v[q] = float4{0.f, 0.f, 0.f, 0.f};
            }
            const int sw = le & 7;
            unsigned short* row = inrow + le * 128;
#pragma unroll
            for (int q = 0; q < 4; ++q) {
                bf16x8 c;
                const float4 va = v[2 * q], vb = v[2 * q + 1];
                c[0] = (short)f2bf(va.x); c[1] = (short)f2bf(va.y);
                c[2] = (short)f2bf(va.z); c[3] = (short)f2bf(va.w);
                c[4] = (short)f2bf(vb.x); c[5] = (short)f2bf(vb.y);
                c[6] = (short)f2bf(vb.z); c[7] = (short)f2bf(vb.w);
                const int cc = 4 * p + q;
                const int ci = (cc & 8) | ((cc & 7) ^ sw);
                *(bf16x8*)(row + ci * 8) = c;
            }
        }

        // ---- layer 1: 16 MFMAs over K=128 ----
        const unsigned short* brow = inrow + el * 128;
        const int sw7 = el & 7;
        f32x4 a0 = bias1[0], a1 = bias1[1], a2 = bias1[2], a3 = bias1[3];
#pragma unroll
        for (int ks = 0; ks < 4; ++ks) {
            const int cc = ks * 4 + g;
            const int ci = (cc & 8) | ((cc & 7) ^ sw7);
            const bf16x8 bf = *(const bf16x8*)(brow + ci * 8);
            a0 = __builtin_amdgcn_mfma_f32_16x16x32_bf16(wa[0][ks], bf, a0, 0, 0, 0);
            a1 = __builtin_amdgcn_mfma_f32_16x16x32_bf16(wa[1][ks], bf, a1, 0, 0, 0);
            a2 = __builtin_amdgcn_mfma_f32_16x16x32_bf16(wa[2][ks], bf, a2, 0, 0, 0);
            a3 = __builtin_amdgcn_mfma_f32_16x16x32_bf16(wa[3][ks], bf, a3, 0, 0, 0);
        }

        // ---- relu -> bf16 -> H (swizzled by el&7) ----
        unsigned short* hrow = hrow0 + el * 64;
        {
            f32x4 accs[4] = {a0, a1, a2, a3};
#pragma unroll
            for (int mt = 0; mt < 4; ++mt) {
                unsigned short pk[4];
#pragma unroll
                for (int r = 0; r < 4; ++r) pk[r] = f2bf(fmaxf(accs[mt][r], 0.f));
                const int hid   = mt * 16 + 4 * g;
                const int chunk = hid >> 3;
                const int off   = hid & 7;
                *(uint2*)(hrow + ((chunk ^ sw7) * 8 + off)) = *(uint2*)pk;
            }
        }

        // ---- layer 2 operand-swapped: D = H (A) x W2b (B) -> node-major ----
        const bf16x8 hb0 = *(const bf16x8*)(hrow + (((0 + g) ^ sw7) * 8));
        const bf16x8 hb1 = *(const bf16x8*)(hrow + (((4 + g) ^ sw7) * 8));
        f32x4 dn0 = {bias2s[0], bias2s[0], bias2s[0], bias2s[0]};
        f32x4 dn1 = {bias2s[1], bias2s[1], bias2s[1], bias2s[1]};
        dn0 = __builtin_amdgcn_mfma_f32_16x16x32_bf16(hb0, wb[0][0], dn0, 0, 0, 0);
        dn1 = __builtin_amdgcn_mfma_f32_16x16x32_bf16(hb0, wb[1][0], dn1, 0, 0, 0);
        dn0 = __builtin_amdgcn_mfma_f32_16x16x32_bf16(hb1, wb[0][1], dn0, 0, 0, 0);
        dn1 = __builtin_amdgcn_mfma_f32_16x16x32_bf16(hb1, wb[1][1], dn1, 0, 0, 0);

        // ---- store: lane holds node 4g+r, out nt*16+el ----
        if (nbase + 16 <= N) {
#pragma unroll
            for (int r = 0; r < 4; ++r) {
                float* dst = out + (size_t)(nbase + 4 * g + r) * 32 + el;
                dst[0]  = dn0[r];
                dst[16] = dn1[r];
            }
        } else {
#pragma unroll
            for (int r = 0; r < 4; ++r) {
                const int n = nbase + 4 * g + r;
                if (n < N) {
                    float* dst = out + (size_t)n * 32 + el;
                    dst[0]  = dn0[r];
                    dst[16] = dn1[r];
                }
            }
        }
    }
}

extern "C" void kernel_launch(void* const* d_in, const int* in_sizes, int n_in,
                              void* d_out, int out_size, void* d_ws, size_t ws_size,
                              hipStream_t stream) {
    const float* x     = (const float*)d_in[0];
    const int*   eidx  = (const int*)d_in[1];   // [2,E] int32
    const float* eattr = (const float*)d_in[2];
    const float* u     = (const float*)d_in[3];
    const int*   batch = (const int*)d_in[4];
    const float* W1a   = (const float*)d_in[5];
    const float* b1a   = (const float*)d_in[6];
    const float* W1b   = (const float*)d_in[7];
    const float* b1b   = (const float*)d_in[8];
    const float* W2a   = (const float*)d_in[9];
    const float* b2a   = (const float*)d_in[10];
    const float* W2b   = (const float*)d_in[11];
    const float* b2b   = (const float*)d_in[12];
    float* out = (float*)d_out;

    const int N = in_sizes[0] / 32;
    const int E = in_sizes[1] / 2;
    const int* erow = eidx;
    const int* ecol = eidx + E;

    // ws: sorted4[E] | summed[N*64] f32 | counts[N] | rowstart[N+1] | cursor[N] | bsum[256]
    int4*  sorted4  = (int4*)d_ws;
    float* summed   = (float*)(sorted4 + E);
    int*   counts   = (int*)(summed + (size_t)N * 64);
    int*   rowstart = counts + N;
    int*   cursor   = rowstart + (N + 1);
    int*   bsum     = cursor + N;

    // zero summed + counts (contiguous)
    hipMemsetAsync(summed, 0, ((size_t)N * 64 + N) * sizeof(float), stream);

    count_rows<<<1024, 256, 0, stream>>>(erow, counts, E);
    const int nb = (N + 255) / 256;
    scan_blocks<<<nb, 256, 0, stream>>>(counts, rowstart, bsum, N);
    scan_bsum<<<1, 256, 0, stream>>>(bsum, nb);
    scan_add<<<nb, 256, 0, stream>>>(rowstart, bsum, N, E);
    hipMemcpyAsync(cursor, rowstart, (size_t)N * sizeof(int),
                   hipMemcpyDeviceToDevice, stream);
    permute_edges<<<1024, 256, 0, stream>>>(erow, ecol, cursor, sorted4, E);

    edge_mlp_mfma<<<1280, 256, 0, stream>>>(x, sorted4, eattr,
                                            W1a, b1a, W1b, b1b, summed, E);
    node_mlp_mfma<<<784, 256, 0, stream>>>(x, summed, rowstart, u, batch,
                                           W2a, b2a, W2b, b2b, out, N);
}

// Round 9
// 403.506 us; speedup vs baseline: 1.2418x; 1.2418x over previous
//
#include <hip/hip_runtime.h>
#include <hip/hip_bf16.h>

// NodeModel: edge MLP ([x[col]||edge_attr] -> 64 relu -> 64 relu) -> scatter_mean
// over row -> node MLP ([x||agg||u[batch]] -> 64 relu -> 32).
// N=50000, E=1.6M, D_H=64.
//
// R9: R8's LDS overlay kept (In/H2/D2 -> one 4352B/wave scratch, 17KB/block)
// but __launch_bounds__(256,4): R8's (256,5) capped VGPR at 48 < the ~84 the
// kernel needs -> weight fragments spilled to scratch -> FETCH 186->865MB,
// dur 190->300us. (256,4) caps at 128: no spill, 4 blocks/CU, 16 waves/CU
// (R5 was 12). Grid back to 4096.

typedef __attribute__((ext_vector_type(8))) short bf16x8;
typedef __attribute__((ext_vector_type(4))) float f32x4;

__device__ __forceinline__ unsigned short f2bf(float f) {
    union { float f; unsigned u; } v; v.f = f;
    return (unsigned short)((v.u + 0x7FFFu + ((v.u >> 16) & 1u)) >> 16);
}

// ---------------- counting sort ----------------

__global__ __launch_bounds__(256) void count_rows(
    const int* __restrict__ erow, int* __restrict__ counts, int E)
{
    const int gid = blockIdx.x * blockDim.x + threadIdx.x;
    const int stride = gridDim.x * blockDim.x;
    const int n4 = E >> 2;
    for (int i = gid; i < n4; i += stride) {
        const int4 r = ((const int4*)erow)[i];
        atomicAdd(&counts[r.x], 1);
        atomicAdd(&counts[r.y], 1);
        atomicAdd(&counts[r.z], 1);
        atomicAdd(&counts[r.w], 1);
    }
    for (int i = (n4 << 2) + gid; i < E; i += stride)
        atomicAdd(&counts[erow[i]], 1);
}

__global__ __launch_bounds__(256) void scan_blocks(
    const int* __restrict__ counts, int* __restrict__ excl,
    int* __restrict__ bsum, int N)
{
    __shared__ int tmp[256];
    const int t = threadIdx.x;
    const int i = blockIdx.x * 256 + t;
    const int v = (i < N) ? counts[i] : 0;
    tmp[t] = v; __syncthreads();
#pragma unroll
    for (int o = 1; o < 256; o <<= 1) {
        const int a = (t >= o) ? tmp[t - o] : 0;
        __syncthreads();
        tmp[t] += a;
        __syncthreads();
    }
    if (i < N) excl[i] = tmp[t] - v;
    if (t == 255) bsum[blockIdx.x] = tmp[t];
}

__global__ __launch_bounds__(256) void scan_bsum(int* __restrict__ bsum, int nb)
{
    __shared__ int tmp[256];
    const int t = threadIdx.x;
    const int v = (t < nb) ? bsum[t] : 0;
    tmp[t] = v; __syncthreads();
#pragma unroll
    for (int o = 1; o < 256; o <<= 1) {
        const int a = (t >= o) ? tmp[t - o] : 0;
        __syncthreads();
        tmp[t] += a;
        __syncthreads();
    }
    if (t < nb) bsum[t] = tmp[t] - v;   // exclusive
}

__global__ __launch_bounds__(256) void scan_add(
    int* __restrict__ rowstart, const int* __restrict__ bsum, int N, int E)
{
    const int i = blockIdx.x * 256 + threadIdx.x;
    if (i < N) rowstart[i] += bsum[blockIdx.x];
    if (i == 0) rowstart[N] = E;
}

// sorted4[pos] = {edge_id, col, row, 0}
__global__ __launch_bounds__(256) void permute_edges(
    const int* __restrict__ erow, const int* __restrict__ ecol,
    int* __restrict__ cursor, int4* __restrict__ sorted4, int E)
{
    const int gid = blockIdx.x * blockDim.x + threadIdx.x;
    const int stride = gridDim.x * blockDim.x;
    const int n4 = E >> 2;
    for (int i = gid; i < n4; i += stride) {
        const int4 r = ((const int4*)erow)[i];
        const int4 c = ((const int4*)ecol)[i];
        const int e0 = i << 2;
        int pos;
        pos = atomicAdd(&cursor[r.x], 1); sorted4[pos] = int4{e0,     c.x, r.x, 0};
        pos = atomicAdd(&cursor[r.y], 1); sorted4[pos] = int4{e0 + 1, c.y, r.y, 0};
        pos = atomicAdd(&cursor[r.z], 1); sorted4[pos] = int4{e0 + 2, c.z, r.z, 0};
        pos = atomicAdd(&cursor[r.w], 1); sorted4[pos] = int4{e0 + 3, c.w, r.w, 0};
    }
    for (int i = (n4 << 2) + gid; i < E; i += stride) {
        const int r = erow[i];
        const int pos = atomicAdd(&cursor[r], 1);
        sorted4[pos] = int4{i, ecol[i], r, 0};
    }
}

// ---------------- edge MLP (sorted) + segment-reduced scatter ----------------

#define D2S 68                 // D2 row stride (floats); breaks store conflicts
#define WV_SCR (D2S * 16 * 4)  // 4352 B per-wave scratch (In/H2/D2 overlaid)

__global__ __launch_bounds__(256, 4) void edge_mlp_mfma(
    const float* __restrict__ x,        // [N,32]
    const int4*  __restrict__ sorted4,  // [E] {eid,col,row,0}
    const float* __restrict__ eattr,    // [E,32]
    const float* __restrict__ W1a,      // [64,64] (in,out)
    const float* __restrict__ b1a,      // [64]
    const float* __restrict__ W1b,      // [64,64]
    const float* __restrict__ b1b,      // [64]
    float* __restrict__ summed,         // [N,64]
    int E)
{
    // One scratch; per-wave 4352B region reused in 3 sequential phases/tile:
    //   phase A: In  bf16[16][64] @ bytes [0,2048)
    //   phase B: H2  bf16[16][64] @ bytes [2048,4096)
    //   phase C: D2  f32 [16][68] @ bytes [0,4352)   (overlaps A and B)
    __shared__ __align__(16) char SCR[4 * WV_SCR];

    const int tid  = threadIdx.x;
    const int lane = tid & 63;
    const int wv   = tid >> 6;
    const int g    = lane >> 4;
    const int el   = lane & 15;

    char* const wbase = SCR + wv * WV_SCR;
    unsigned short* const inw = (unsigned short*)wbase;           // [16][64]
    unsigned short* const h2w = (unsigned short*)(wbase + 2048);  // [16][64]
    float*          const d2w = (float*)wbase;                    // [16][68]

    // persistent weight fragments: A row = lane&15, k = 8*(lane>>4)+j;
    // B col = lane&15, same k (identical mappings)
    bf16x8 wa[4][2], wb[4][2];
    f32x4  bias1[4];
    float  bias2s[4];
#pragma unroll
    for (int mt = 0; mt < 4; ++mt) {
        const int o = mt * 16 + el;
#pragma unroll
        for (int ks = 0; ks < 2; ++ks) {
            bf16x8 ta, tb;
#pragma unroll
            for (int j = 0; j < 8; ++j) {
                const int k = ks * 32 + 8 * g + j;
                ta[j] = (short)f2bf(W1a[k * 64 + o]);
                tb[j] = (short)f2bf(W1b[k * 64 + o]);
            }
            wa[mt][ks] = ta;
            wb[mt][ks] = tb;
        }
#pragma unroll
        for (int r = 0; r < 4; ++r) bias1[mt][r] = b1a[mt * 16 + 4 * g + r];
        bias2s[mt] = b1b[o];
    }

    const int ntile = (E + 15) >> 4;
    const int wid   = blockIdx.x * 4 + wv;
    const int nw    = gridDim.x * 4;

    for (int t = wid; t < ntile; t += nw) {
        const int ebase = t << 4;

        // ---- stage 16 sorted edges: 4 lanes/edge -> bf16 -> swizzled LDS ----
        {
            const int le  = lane >> 2;
            const int p   = lane & 3;
            const int pos = ebase + le;
            float4 v[4];
            if (pos < E) {
                const int4 s4 = sorted4[pos];
                const float* src;
                if (p < 2) src = x + (size_t)s4.y * 32 + p * 16;
                else       src = eattr + (size_t)s4.x * 32 + (p - 2) * 16;
#pragma unroll
                for (int q = 0; q < 4; ++q) v[q] = ((const float4*)src)[q];
            } else {
#pragma unroll
                for (int q = 0; q < 4; ++q) v[q] = float4{0.f, 0.f, 0.f, 0.f};
            }
            bf16x8 c0, c1;
#pragma unroll
            for (int q = 0; q < 2; ++q) {
                c0[4*q+0] = (short)f2bf(v[q].x);   c0[4*q+1] = (short)f2bf(v[q].y);
                c0[4*q+2] = (short)f2bf(v[q].z);   c0[4*q+3] = (short)f2bf(v[q].w);
                c1[4*q+0] = (short)f2bf(v[q+2].x); c1[4*q+1] = (short)f2bf(v[q+2].y);
                c1[4*q+2] = (short)f2bf(v[q+2].z); c1[4*q+3] = (short)f2bf(v[q+2].w);
            }
            const int sw = le & 7;
            unsigned short* row = inw + le * 64;
            *(bf16x8*)(row + (((2 * p)     ^ sw) * 8)) = c0;
            *(bf16x8*)(row + (((2 * p + 1) ^ sw) * 8)) = c1;
        }
        // wave-private LDS: in-order DS pipe + compiler lgkmcnt, no barrier

        const int sw = el & 7;

        // ---- layer 1: D1 = W1a^T (A) x In^T (B) -> neuron-major ----
        const unsigned short* brow = inw + el * 64;
        const bf16x8 bf0 = *(const bf16x8*)(brow + (((0 + g) ^ sw) * 8));
        const bf16x8 bf1 = *(const bf16x8*)(brow + (((4 + g) ^ sw) * 8));
        f32x4 a0 = bias1[0], a1 = bias1[1], a2 = bias1[2], a3 = bias1[3];
        a0 = __builtin_amdgcn_mfma_f32_16x16x32_bf16(wa[0][0], bf0, a0, 0, 0, 0);
        a1 = __builtin_amdgcn_mfma_f32_16x16x32_bf16(wa[1][0], bf0, a1, 0, 0, 0);
        a2 = __builtin_amdgcn_mfma_f32_16x16x32_bf16(wa[2][0], bf0, a2, 0, 0, 0);
        a3 = __builtin_amdgcn_mfma_f32_16x16x32_bf16(wa[3][0], bf0, a3, 0, 0, 0);
        a0 = __builtin_amdgcn_mfma_f32_16x16x32_bf16(wa[0][1], bf1, a0, 0, 0, 0);
        a1 = __builtin_amdgcn_mfma_f32_16x16x32_bf16(wa[1][1], bf1, a1, 0, 0, 0);
        a2 = __builtin_amdgcn_mfma_f32_16x16x32_bf16(wa[2][1], bf1, a2, 0, 0, 0);
        a3 = __builtin_amdgcn_mfma_f32_16x16x32_bf16(wa[3][1], bf1, a3, 0, 0, 0);

        // ---- relu -> bf16 -> H2 (wave-private, swizzled) ----
        unsigned short* hrow = h2w + el * 64;
        {
            f32x4 accs[4] = {a0, a1, a2, a3};
#pragma unroll
            for (int mt = 0; mt < 4; ++mt) {
                unsigned short pk[4];
#pragma unroll
                for (int r = 0; r < 4; ++r) pk[r] = f2bf(fmaxf(accs[mt][r], 0.f));
                const int hid   = mt * 16 + 4 * g;
                const int chunk = hid >> 3;
                const int off   = hid & 7;
                *(uint2*)(hrow + ((chunk ^ sw) * 8 + off)) = *(uint2*)pk;
            }
        }

        // ---- layer 2, operand-swapped: D2 = H1 (A) x W1b (B) -> EDGE-major ----
        const bf16x8 hb0 = *(const bf16x8*)(hrow + (((0 + g) ^ sw) * 8));
        const bf16x8 hb1 = *(const bf16x8*)(hrow + (((4 + g) ^ sw) * 8));
        f32x4 d0 = {bias2s[0], bias2s[0], bias2s[0], bias2s[0]};
        f32x4 d1 = {bias2s[1], bias2s[1], bias2s[1], bias2s[1]};
        f32x4 d2 = {bias2s[2], bias2s[2], bias2s[2], bias2s[2]};
        f32x4 d3 = {bias2s[3], bias2s[3], bias2s[3], bias2s[3]};
        d0 = __builtin_amdgcn_mfma_f32_16x16x32_bf16(hb0, wb[0][0], d0, 0, 0, 0);
        d1 = __builtin_amdgcn_mfma_f32_16x16x32_bf16(hb0, wb[1][0], d1, 0, 0, 0);
        d2 = __builtin_amdgcn_mfma_f32_16x16x32_bf16(hb0, wb[2][0], d2, 0, 0, 0);
        d3 = __builtin_amdgcn_mfma_f32_16x16x32_bf16(hb0, wb[3][0], d3, 0, 0, 0);
        d0 = __builtin_amdgcn_mfma_f32_16x16x32_bf16(hb1, wb[0][1], d0, 0, 0, 0);
        d1 = __builtin_amdgcn_mfma_f32_16x16x32_bf16(hb1, wb[1][1], d1, 0, 0, 0);
        d2 = __builtin_amdgcn_mfma_f32_16x16x32_bf16(hb1, wb[2][1], d2, 0, 0, 0);
        d3 = __builtin_amdgcn_mfma_f32_16x16x32_bf16(hb1, wb[3][1], d3, 0, 0, 0);

        // ---- relu -> D2 f32[16][68] (overlays In+H2; phase-ordered) ----
        {
            f32x4 dd[4] = {d0, d1, d2, d3};
#pragma unroll
            for (int nt = 0; nt < 4; ++nt)
#pragma unroll
                for (int r = 0; r < 4; ++r) {
                    const int eg = ebase + 4 * g + r;
                    d2w[(4 * g + r) * D2S + nt * 16 + el] =
                        (eg < E) ? fmaxf(dd[nt][r], 0.f) : 0.f;
                }
        }

        // ---- segment flush: rows are sorted runs; lane = neuron ----
        const int myrow = (ebase + el < E) ? sorted4[ebase + el].z : -1;
        float acc = 0.f;
        int prev = __shfl(myrow, 0);
#pragma unroll
        for (int j = 0; j < 16; ++j) {
            const float v = d2w[j * D2S + lane];
            const int rj = __shfl(myrow, j);
            if (rj != prev) {                        // wave-uniform branch
                if (prev >= 0)
                    unsafeAtomicAdd(&summed[(size_t)prev * 64 + lane], acc);
                acc = 0.f;
                prev = rj;
            }
            acc += v;
        }
        if (prev >= 0)
            unsafeAtomicAdd(&summed[(size_t)prev * 64 + lane], acc);
    }
}

// ---------------- node MLP via MFMA ----------------

__global__ __launch_bounds__(256, 2) void node_mlp_mfma(
    const float* __restrict__ x,        // [N,32]
    const float* __restrict__ summed,   // [N,64]
    const int*   __restrict__ rowstart, // [N+1]
    const float* __restrict__ u,        // [G,16]
    const int*   __restrict__ batch,    // [N]
    const float* __restrict__ W2a,      // [112,64]
    const float* __restrict__ b2a,      // [64]
    const float* __restrict__ W2b,      // [64,32]
    const float* __restrict__ b2b,      // [32]
    float* __restrict__ out,            // [N,32]
    int N)
{
    __shared__ __align__(16) unsigned short In[64 * 128];  // 16KB
    __shared__ __align__(16) unsigned short H[64 * 64];    // 8KB

    const int tid  = threadIdx.x;
    const int lane = tid & 63;
    const int wv   = tid >> 6;
    const int g    = lane >> 4;
    const int el   = lane & 15;

    bf16x8 wa[4][4];
    f32x4  bias1[4];
#pragma unroll
    for (int mt = 0; mt < 4; ++mt) {
        const int o = mt * 16 + el;
#pragma unroll
        for (int ks = 0; ks < 4; ++ks) {
            bf16x8 ta;
#pragma unroll
            for (int j = 0; j < 8; ++j) {
                const int k = ks * 32 + 8 * g + j;
                ta[j] = (k < 112) ? (short)f2bf(W2a[k * 64 + o]) : (short)0;
            }
            wa[mt][ks] = ta;
        }
#pragma unroll
        for (int r = 0; r < 4; ++r) bias1[mt][r] = b2a[mt * 16 + 4 * g + r];
    }
    bf16x8 wb[2][2];
    float  bias2s[2];
#pragma unroll
    for (int nt = 0; nt < 2; ++nt) {
        const int o = nt * 16 + el;
#pragma unroll
        for (int ks = 0; ks < 2; ++ks) {
            bf16x8 tb;
#pragma unroll
            for (int j = 0; j < 8; ++j) {
                const int k = ks * 32 + 8 * g + j;
                tb[j] = (short)f2bf(W2b[k * 32 + o]);
            }
            wb[nt][ks] = tb;
        }
        bias2s[nt] = b2b[o];
    }

    unsigned short* const inrow = In + (wv * 16) * 128;
    unsigned short* const hrow0 = H + (wv * 16) * 64;

    const int ntile = (N + 15) >> 4;
    const int wid   = blockIdx.x * 4 + wv;
    const int nw    = gridDim.x * 4;

    for (int t = wid; t < ntile; t += nw) {
        const int nbase = t << 4;

        // ---- stage 16 nodes: 4 lanes/node, 32-float segment each ----
        // row layout (128 bf16): [x(32) | agg(32) | agg(32) | u(16)+0(16)]
        {
            const int le = lane >> 2;
            const int p  = lane & 3;
            const int n  = nbase + le;
            float4 v[8];
            if (n < N) {
                if (p == 0) {
                    const float4* xp = (const float4*)(x + (size_t)n * 32);
#pragma unroll
                    for (int q = 0; q < 8; ++q) v[q] = xp[q];
                } else if (p < 3) {
                    const int cnt = rowstart[n + 1] - rowstart[n];
                    const float inv = 1.0f / fmaxf((float)cnt, 1.0f);
                    const float4* sp = (const float4*)(summed + (size_t)n * 64 + (p - 1) * 32);
#pragma unroll
                    for (int q = 0; q < 8; ++q) {
                        v[q] = sp[q];
                        v[q].x *= inv; v[q].y *= inv; v[q].z *= inv; v[q].w *= inv;
                    }
                } else {
                    const int gb = batch[n];
                    const float4* up = (const float4*)(u + (size_t)gb * 16);
#pragma unroll
                    for (int q = 0; q < 4; ++q) v[q] = up[q];
#pragma unroll
                    for (int q = 4; q < 8; ++q) v[q] = float4{0.f, 0.f, 0.f, 0.f};
                }
            } else {
#pragma unroll
                for (int q = 0; q < 8; ++q) v[q] = float4{0.f, 0.f, 0.f, 0.f};
            }
            const int sw = le & 7;
            unsigned short* row = inrow + le * 128;
#pragma unroll
            for (int q = 0; q < 4; ++q) {
                bf16x8 c;
                const float4 va = v[2 * q], vb = v[2 * q + 1];
                c[0] = (short)f2bf(va.x); c[1] = (short)f2bf(va.y);
                c[2] = (short)f2bf(va.z); c[3] = (short)f2bf(va.w);
                c[4] = (short)f2bf(vb.x); c[5] = (short)f2bf(vb.y);
                c[6] = (short)f2bf(vb.z); c[7] = (short)f2bf(vb.w);
                const int cc = 4 * p + q;
                const int ci = (cc & 8) | ((cc & 7) ^ sw);
                *(bf16x8*)(row + ci * 8) = c;
            }
        }

        // ---- layer 1: 16 MFMAs over K=128 ----
        const unsigned short* brow = inrow + el * 128;
        const int sw7 = el & 7;
        f32x4 a0 = bias1[0], a1 = bias1[1], a2 = bias1[2], a3 = bias1[3];
#pragma unroll
        for (int ks = 0; ks < 4; ++ks) {
            const int cc = ks * 4 + g;
            const int ci = (cc & 8) | ((cc & 7) ^ sw7);
            const bf16x8 bf = *(const bf16x8*)(brow + ci * 8);
            a0 = __builtin_amdgcn_mfma_f32_16x16x32_bf16(wa[0][ks], bf, a0, 0, 0, 0);
            a1 = __builtin_amdgcn_mfma_f32_16x16x32_bf16(wa[1][ks], bf, a1, 0, 0, 0);
            a2 = __builtin_amdgcn_mfma_f32_16x16x32_bf16(wa[2][ks], bf, a2, 0, 0, 0);
            a3 = __builtin_amdgcn_mfma_f32_16x16x32_bf16(wa[3][ks], bf, a3, 0, 0, 0);
        }

        // ---- relu -> bf16 -> H (swizzled by el&7) ----
        unsigned short* hrow = hrow0 + el * 64;
        {
            f32x4 accs[4] = {a0, a1, a2, a3};
#pragma unroll
            for (int mt = 0; mt < 4; ++mt) {
                unsigned short pk[4];
#pragma unroll
                for (int r = 0; r < 4; ++r) pk[r] = f2bf(fmaxf(accs[mt][r], 0.f));
                const int hid   = mt * 16 + 4 * g;
                const int chunk = hid >> 3;
                const int off   = hid & 7;
                *(uint2*)(hrow + ((chunk ^ sw7) * 8 + off)) = *(uint2*)pk;
            }
        }

        // ---- layer 2 operand-swapped: D = H (A) x W2b (B) -> node-major ----
        const bf16x8 hb0 = *(const bf16x8*)(hrow + (((0 + g) ^ sw7) * 8));
        const bf16x8 hb1 = *(const bf16x8*)(hrow + (((4 + g) ^ sw7) * 8));
        f32x4 dn0 = {bias2s[0], bias2s[0], bias2s[0], bias2s[0]};
        f32x4 dn1 = {bias2s[1], bias2s[1], bias2s[1], bias2s[1]};
        dn0 = __builtin_amdgcn_mfma_f32_16x16x32_bf16(hb0, wb[0][0], dn0, 0, 0, 0);
        dn1 = __builtin_amdgcn_mfma_f32_16x16x32_bf16(hb0, wb[1][0], dn1, 0, 0, 0);
        dn0 = __builtin_amdgcn_mfma_f32_16x16x32_bf16(hb1, wb[0][1], dn0, 0, 0, 0);
        dn1 = __builtin_amdgcn_mfma_f32_16x16x32_bf16(hb1, wb[1][1], dn1, 0, 0, 0);

        // ---- store: lane holds node 4g+r, out nt*16+el ----
        if (nbase + 16 <= N) {
#pragma unroll
            for (int r = 0; r < 4; ++r) {
                float* dst = out + (size_t)(nbase + 4 * g + r) * 32 + el;
                dst[0]  = dn0[r];
                dst[16] = dn1[r];
            }
        } else {
#pragma unroll
            for (int r = 0; r < 4; ++r) {
                const int n = nbase + 4 * g + r;
                if (n < N) {
                    float* dst = out + (size_t)n * 32 + el;
                    dst[0]  = dn0[r];
                    dst[16] = dn1[r];
                }
            }
        }
    }
}

extern "C" void kernel_launch(void* const* d_in, const int* in_sizes, int n_in,
                              void* d_out, int out_size, void* d_ws, size_t ws_size,
                              hipStream_t stream) {
    const float* x     = (const float*)d_in[0];
    const int*   eidx  = (const int*)d_in[1];   // [2,E] int32
    const float* eattr = (const float*)d_in[2];
    const float* u     = (const float*)d_in[3];
    const int*   batch = (const int*)d_in[4];
    const float* W1a   = (const float*)d_in[5];
    const float* b1a   = (const float*)d_in[6];
    const float* W1b   = (const float*)d_in[7];
    const float* b1b   = (const float*)d_in[8];
    const float* W2a   = (const float*)d_in[9];
    const float* b2a   = (const float*)d_in[10];
    const float* W2b   = (const float*)d_in[11];
    const float* b2b   = (const float*)d_in[12];
    float* out = (float*)d_out;

    const int N = in_sizes[0] / 32;
    const int E = in_sizes[1] / 2;
    const int* erow = eidx;
    const int* ecol = eidx + E;

    // ws: sorted4[E] | summed[N*64] f32 | counts[N] | rowstart[N+1] | cursor[N] | bsum[256]
    int4*  sorted4  = (int4*)d_ws;
    float* summed   = (float*)(sorted4 + E);
    int*   counts   = (int*)(summed + (size_t)N * 64);
    int*   rowstart = counts + N;
    int*   cursor   = rowstart + (N + 1);
    int*   bsum     = cursor + N;

    // zero summed + counts (contiguous)
    hipMemsetAsync(summed, 0, ((size_t)N * 64 + N) * sizeof(float), stream);

    count_rows<<<1024, 256, 0, stream>>>(erow, counts, E);
    const int nb = (N + 255) / 256;
    scan_blocks<<<nb, 256, 0, stream>>>(counts, rowstart, bsum, N);
    scan_bsum<<<1, 256, 0, stream>>>(bsum, nb);
    scan_add<<<nb, 256, 0, stream>>>(rowstart, bsum, N, E);
    hipMemcpyAsync(cursor, rowstart, (size_t)N * sizeof(int),
                   hipMemcpyDeviceToDevice, stream);
    permute_edges<<<1024, 256, 0, stream>>>(erow, ecol, cursor, sorted4, E);

    edge_mlp_mfma<<<4096, 256, 0, stream>>>(x, sorted4, eattr,
                                            W1a, b1a, W1b, b1b, summed, E);
    node_mlp_mfma<<<784, 256, 0, stream>>>(x, summed, rowstart, u, batch,
                                           W2a, b2a, W2b, b2b, out, N);
}

// Round 10
// 383.832 us; speedup vs baseline: 1.3054x; 1.0513x over previous
//
#include <hip/hip_runtime.h>
#include <hip/hip_bf16.h>

// NodeModel: edge MLP ([x[col]||edge_attr] -> 64 relu -> 64 relu) -> scatter_mean
// over row -> node MLP ([x||agg||u[batch]] -> 64 relu -> 32).
// N=50000, E=1.6M, D_H=64.
//
// R10: back to R5's no-spill operating point ((256,3), ~84+ VGPR) but with
// TWO independent 16-edge sub-tiles per loop iteration (32 contiguous sorted
// edges): both random gathers in flight together, two independent
// MFMA/LDS chains for the scheduler to interleave -> per-edge latency ~halved
// at unchanged occupancy. R8/R9 proved occupancy>12 waves/CU costs spills
// (FETCH 186->348/865MB); R6 proved cross-iteration pipelining spills too.
// Flush rows now come from staging lanes via __shfl (kills the second
// sorted4 read, -25MB FETCH); one 32-edge flush merges boundary runs.

typedef __attribute__((ext_vector_type(8))) short bf16x8;
typedef __attribute__((ext_vector_type(4))) float f32x4;

__device__ __forceinline__ unsigned short f2bf(float f) {
    union { float f; unsigned u; } v; v.f = f;
    return (unsigned short)((v.u + 0x7FFFu + ((v.u >> 16) & 1u)) >> 16);
}

// ---------------- counting sort ----------------

__global__ __launch_bounds__(256) void count_rows(
    const int* __restrict__ erow, int* __restrict__ counts, int E)
{
    const int gid = blockIdx.x * blockDim.x + threadIdx.x;
    const int stride = gridDim.x * blockDim.x;
    const int n4 = E >> 2;
    for (int i = gid; i < n4; i += stride) {
        const int4 r = ((const int4*)erow)[i];
        atomicAdd(&counts[r.x], 1);
        atomicAdd(&counts[r.y], 1);
        atomicAdd(&counts[r.z], 1);
        atomicAdd(&counts[r.w], 1);
    }
    for (int i = (n4 << 2) + gid; i < E; i += stride)
        atomicAdd(&counts[erow[i]], 1);
}

__global__ __launch_bounds__(256) void scan_blocks(
    const int* __restrict__ counts, int* __restrict__ excl,
    int* __restrict__ bsum, int N)
{
    __shared__ int tmp[256];
    const int t = threadIdx.x;
    const int i = blockIdx.x * 256 + t;
    const int v = (i < N) ? counts[i] : 0;
    tmp[t] = v; __syncthreads();
#pragma unroll
    for (int o = 1; o < 256; o <<= 1) {
        const int a = (t >= o) ? tmp[t - o] : 0;
        __syncthreads();
        tmp[t] += a;
        __syncthreads();
    }
    if (i < N) excl[i] = tmp[t] - v;
    if (t == 255) bsum[blockIdx.x] = tmp[t];
}

__global__ __launch_bounds__(256) void scan_bsum(int* __restrict__ bsum, int nb)
{
    __shared__ int tmp[256];
    const int t = threadIdx.x;
    const int v = (t < nb) ? bsum[t] : 0;
    tmp[t] = v; __syncthreads();
#pragma unroll
    for (int o = 1; o < 256; o <<= 1) {
        const int a = (t >= o) ? tmp[t - o] : 0;
        __syncthreads();
        tmp[t] += a;
        __syncthreads();
    }
    if (t < nb) bsum[t] = tmp[t] - v;   // exclusive
}

__global__ __launch_bounds__(256) void scan_add(
    int* __restrict__ rowstart, const int* __restrict__ bsum, int N, int E)
{
    const int i = blockIdx.x * 256 + threadIdx.x;
    if (i < N) rowstart[i] += bsum[blockIdx.x];
    if (i == 0) rowstart[N] = E;
}

// sorted4[pos] = {edge_id, col, row, 0}
__global__ __launch_bounds__(256) void permute_edges(
    const int* __restrict__ erow, const int* __restrict__ ecol,
    int* __restrict__ cursor, int4* __restrict__ sorted4, int E)
{
    const int gid = blockIdx.x * blockDim.x + threadIdx.x;
    const int stride = gridDim.x * blockDim.x;
    const int n4 = E >> 2;
    for (int i = gid; i < n4; i += stride) {
        const int4 r = ((const int4*)erow)[i];
        const int4 c = ((const int4*)ecol)[i];
        const int e0 = i << 2;
        int pos;
        pos = atomicAdd(&cursor[r.x], 1); sorted4[pos] = int4{e0,     c.x, r.x, 0};
        pos = atomicAdd(&cursor[r.y], 1); sorted4[pos] = int4{e0 + 1, c.y, r.y, 0};
        pos = atomicAdd(&cursor[r.z], 1); sorted4[pos] = int4{e0 + 2, c.z, r.z, 0};
        pos = atomicAdd(&cursor[r.w], 1); sorted4[pos] = int4{e0 + 3, c.w, r.w, 0};
    }
    for (int i = (n4 << 2) + gid; i < E; i += stride) {
        const int r = erow[i];
        const int pos = atomicAdd(&cursor[r], 1);
        sorted4[pos] = int4{i, ecol[i], r, 0};
    }
}

// ---------------- edge MLP (sorted, paired sub-tiles) ----------------

#define D2S 68                    // D2 row stride (floats)
#define WV_SCR (D2S * 32 * 4)     // 8704 B per-wave scratch, all phases overlaid

__global__ __launch_bounds__(256, 3) void edge_mlp_mfma(
    const float* __restrict__ x,        // [N,32]
    const int4*  __restrict__ sorted4,  // [E] {eid,col,row,0}
    const float* __restrict__ eattr,    // [E,32]
    const float* __restrict__ W1a,      // [64,64] (in,out)
    const float* __restrict__ b1a,      // [64]
    const float* __restrict__ W1b,      // [64,64]
    const float* __restrict__ b1b,      // [64]
    float* __restrict__ summed,         // [N,64]
    int E)
{
    // Per-wave 8704B scratch, phase-overlaid (in-order DS pipe per wave):
    //   InA bf16[16][64] @ [0,2048)      InB @ [2048,4096)
    //   H2A bf16[16][64] @ [4096,6144)   H2B @ [6144,8192)
    //   D2  f32 [32][68] @ [0,8704)      (written after the reads it overlaps)
    __shared__ __align__(16) char SCR[4 * WV_SCR];

    const int tid  = threadIdx.x;
    const int lane = tid & 63;
    const int wv   = tid >> 6;
    const int g    = lane >> 4;
    const int el   = lane & 15;
    const int le   = lane >> 2;   // staging: local edge 0..15 (per sub-tile)
    const int p    = lane & 3;    // staging: quarter of the 64-wide input row

    char* const wbase = SCR + wv * WV_SCR;
    unsigned short* const inA = (unsigned short*)(wbase);
    unsigned short* const inB = (unsigned short*)(wbase + 2048);
    unsigned short* const h2A = (unsigned short*)(wbase + 4096);
    unsigned short* const h2B = (unsigned short*)(wbase + 6144);
    float*          const d2w = (float*)wbase;               // [32][D2S]

    // persistent weight fragments: A row = lane&15, k = 8*(lane>>4)+j;
    // B col = lane&15, same k (identical mappings)
    bf16x8 wa[4][2], wb[4][2];
    f32x4  bias1[4];
    float  bias2s[4];
#pragma unroll
    for (int mt = 0; mt < 4; ++mt) {
        const int o = mt * 16 + el;
#pragma unroll
        for (int ks = 0; ks < 2; ++ks) {
            bf16x8 ta, tb;
#pragma unroll
            for (int j = 0; j < 8; ++j) {
                const int k = ks * 32 + 8 * g + j;
                ta[j] = (short)f2bf(W1a[k * 64 + o]);
                tb[j] = (short)f2bf(W1b[k * 64 + o]);
            }
            wa[mt][ks] = ta;
            wb[mt][ks] = tb;
        }
#pragma unroll
        for (int r = 0; r < 4; ++r) bias1[mt][r] = b1a[mt * 16 + 4 * g + r];
        bias2s[mt] = b1b[o];
    }

    const int ntile = (E + 31) >> 5;              // 32-edge tiles
    const int wid   = blockIdx.x * 4 + wv;
    const int nw    = gridDim.x * 4;

    const int swl = le & 7;   // staging swizzle
    const int sw  = el & 7;   // compute swizzle

    // gather one 16-edge sub-tile's inputs (64B/lane) + its meta
    auto gather = [&](int eb, int4& s4, float4 v[4]) {
        const int pos = eb + le;
        if (pos < E) {
            s4 = sorted4[pos];
            const float* src = (p < 2) ? x + (size_t)s4.y * 32 + p * 16
                                       : eattr + (size_t)s4.x * 32 + (p - 2) * 16;
#pragma unroll
            for (int q = 0; q < 4; ++q) v[q] = ((const float4*)src)[q];
        } else {
            s4 = int4{0, 0, -1, 0};
#pragma unroll
            for (int q = 0; q < 4; ++q) v[q] = float4{0.f, 0.f, 0.f, 0.f};
        }
    };
    // pack 16 f32 -> bf16, swizzled store into a sub-tile In buffer
    auto stage = [&](unsigned short* inw, const float4 v[4]) {
        bf16x8 c0, c1;
#pragma unroll
        for (int q = 0; q < 2; ++q) {
            c0[4*q+0] = (short)f2bf(v[q].x);   c0[4*q+1] = (short)f2bf(v[q].y);
            c0[4*q+2] = (short)f2bf(v[q].z);   c0[4*q+3] = (short)f2bf(v[q].w);
            c1[4*q+0] = (short)f2bf(v[q+2].x); c1[4*q+1] = (short)f2bf(v[q+2].y);
            c1[4*q+2] = (short)f2bf(v[q+2].z); c1[4*q+3] = (short)f2bf(v[q+2].w);
        }
        unsigned short* row = inw + le * 64;
        *(bf16x8*)(row + (((2 * p)     ^ swl) * 8)) = c0;
        *(bf16x8*)(row + (((2 * p + 1) ^ swl) * 8)) = c1;
    };
    // layer 1 for one sub-tile: In -> relu(W1a^T x In^T) -> H2 (bf16, swizzled)
    auto layer1 = [&](const unsigned short* inw, unsigned short* h2w) {
        const unsigned short* brow = inw + el * 64;
        const bf16x8 bf0 = *(const bf16x8*)(brow + (((0 + g) ^ sw) * 8));
        const bf16x8 bf1 = *(const bf16x8*)(brow + (((4 + g) ^ sw) * 8));
        f32x4 a0 = bias1[0], a1 = bias1[1], a2 = bias1[2], a3 = bias1[3];
        a0 = __builtin_amdgcn_mfma_f32_16x16x32_bf16(wa[0][0], bf0, a0, 0, 0, 0);
        a1 = __builtin_amdgcn_mfma_f32_16x16x32_bf16(wa[1][0], bf0, a1, 0, 0, 0);
        a2 = __builtin_amdgcn_mfma_f32_16x16x32_bf16(wa[2][0], bf0, a2, 0, 0, 0);
        a3 = __builtin_amdgcn_mfma_f32_16x16x32_bf16(wa[3][0], bf0, a3, 0, 0, 0);
        a0 = __builtin_amdgcn_mfma_f32_16x16x32_bf16(wa[0][1], bf1, a0, 0, 0, 0);
        a1 = __builtin_amdgcn_mfma_f32_16x16x32_bf16(wa[1][1], bf1, a1, 0, 0, 0);
        a2 = __builtin_amdgcn_mfma_f32_16x16x32_bf16(wa[2][1], bf1, a2, 0, 0, 0);
        a3 = __builtin_amdgcn_mfma_f32_16x16x32_bf16(wa[3][1], bf1, a3, 0, 0, 0);
        unsigned short* hrow = h2w + el * 64;
        f32x4 accs[4] = {a0, a1, a2, a3};
#pragma unroll
        for (int mt = 0; mt < 4; ++mt) {
            unsigned short pk[4];
#pragma unroll
            for (int r = 0; r < 4; ++r) pk[r] = f2bf(fmaxf(accs[mt][r], 0.f));
            const int hid   = mt * 16 + 4 * g;
            const int chunk = hid >> 3;
            const int off   = hid & 7;
            *(uint2*)(hrow + ((chunk ^ sw) * 8 + off)) = *(uint2*)pk;
        }
    };
    // layer 2 for one sub-tile: H2 -> relu(H1 x W1b) -> D2 rows [rb, rb+16)
    auto layer2 = [&](const unsigned short* h2w, int rb, int ebase) {
        const unsigned short* hrow = h2w + el * 64;
        const bf16x8 hb0 = *(const bf16x8*)(hrow + (((0 + g) ^ sw) * 8));
        const bf16x8 hb1 = *(const bf16x8*)(hrow + (((4 + g) ^ sw) * 8));
        f32x4 d0 = {bias2s[0], bias2s[0], bias2s[0], bias2s[0]};
        f32x4 d1 = {bias2s[1], bias2s[1], bias2s[1], bias2s[1]};
        f32x4 d2 = {bias2s[2], bias2s[2], bias2s[2], bias2s[2]};
        f32x4 d3 = {bias2s[3], bias2s[3], bias2s[3], bias2s[3]};
        d0 = __builtin_amdgcn_mfma_f32_16x16x32_bf16(hb0, wb[0][0], d0, 0, 0, 0);
        d1 = __builtin_amdgcn_mfma_f32_16x16x32_bf16(hb0, wb[1][0], d1, 0, 0, 0);
        d2 = __builtin_amdgcn_mfma_f32_16x16x32_bf16(hb0, wb[2][0], d2, 0, 0, 0);
        d3 = __builtin_amdgcn_mfma_f32_16x16x32_bf16(hb0, wb[3][0], d3, 0, 0, 0);
        d0 = __builtin_amdgcn_mfma_f32_16x16x32_bf16(hb1, wb[0][1], d0, 0, 0, 0);
        d1 = __builtin_amdgcn_mfma_f32_16x16x32_bf16(hb1, wb[1][1], d1, 0, 0, 0);
        d2 = __builtin_amdgcn_mfma_f32_16x16x32_bf16(hb1, wb[2][1], d2, 0, 0, 0);
        d3 = __builtin_amdgcn_mfma_f32_16x16x32_bf16(hb1, wb[3][1], d3, 0, 0, 0);
        f32x4 dd[4] = {d0, d1, d2, d3};
#pragma unroll
        for (int nt = 0; nt < 4; ++nt)
#pragma unroll
            for (int r = 0; r < 4; ++r) {
                const int eg = ebase + rb + 4 * g + r;
                d2w[(rb + 4 * g + r) * D2S + nt * 16 + el] =
                    (eg < E) ? fmaxf(dd[nt][r], 0.f) : 0.f;
            }
    };

    for (int t = wid; t < ntile; t += nw) {
        const int ebase = t << 5;

        // ---- both sub-tile gathers in flight together ----
        int4 s4A, s4B;
        float4 vA[4], vB[4];
        gather(ebase,      s4A, vA);
        gather(ebase + 16, s4B, vB);

        // ---- stage both ----
        stage(inA, vA);
        stage(inB, vB);

        // ---- two independent compute chains (scheduler interleaves) ----
        layer1(inA, h2A);
        layer1(inB, h2B);
        layer2(h2A, 0,  ebase);
        layer2(h2B, 16, ebase);

        // ---- segment flush over 32 sorted edges; rows via shfl from staging ----
        // lane 4*j (p=0) holds s4 of local edge j; OOB rows are -1.
        float acc = 0.f;
        int prev = __shfl(s4A.z, 0);
#pragma unroll
        for (int j = 0; j < 32; ++j) {
            const float v = d2w[j * D2S + lane];
            const int rj = (j < 16) ? __shfl(s4A.z, 4 * j)
                                    : __shfl(s4B.z, 4 * (j - 16));
            if (rj != prev) {                        // wave-uniform branch
                if (prev >= 0)
                    unsafeAtomicAdd(&summed[(size_t)prev * 64 + lane], acc);
                acc = 0.f;
                prev = rj;
            }
            acc += v;
        }
        if (prev >= 0)
            unsafeAtomicAdd(&summed[(size_t)prev * 64 + lane], acc);
    }
}

// ---------------- node MLP via MFMA ----------------

__global__ __launch_bounds__(256, 2) void node_mlp_mfma(
    const float* __restrict__ x,        // [N,32]
    const float* __restrict__ summed,   // [N,64]
    const int*   __restrict__ rowstart, // [N+1]
    const float* __restrict__ u,        // [G,16]
    const int*   __restrict__ batch,    // [N]
    const float* __restrict__ W2a,      // [112,64]
    const float* __restrict__ b2a,      // [64]
    const float* __restrict__ W2b,      // [64,32]
    const float* __restrict__ b2b,      // [32]
    float* __restrict__ out,            // [N,32]
    int N)
{
    __shared__ __align__(16) unsigned short In[64 * 128];  // 16KB
    __shared__ __align__(16) unsigned short H[64 * 64];    // 8KB

    const int tid  = threadIdx.x;
    const int lane = tid & 63;
    const int wv   = tid >> 6;
    const int g    = lane >> 4;
    const int el   = lane & 15;

    bf16x8 wa[4][4];
    f32x4  bias1[4];
#pragma unroll
    for (int mt = 0; mt < 4; ++mt) {
        const int o = mt * 16 + el;
#pragma unroll
        for (int ks = 0; ks < 4; ++ks) {
            bf16x8 ta;
#pragma unroll
            for (int j = 0; j < 8; ++j) {
                const int k = ks * 32 + 8 * g + j;
                ta[j] = (k < 112) ? (short)f2bf(W2a[k * 64 + o]) : (short)0;
            }
            wa[mt][ks] = ta;
        }
#pragma unroll
        for (int r = 0; r < 4; ++r) bias1[mt][r] = b2a[mt * 16 + 4 * g + r];
    }
    bf16x8 wb[2][2];
    float  bias2s[2];
#pragma unroll
    for (int nt = 0; nt < 2; ++nt) {
        const int o = nt * 16 + el;
#pragma unroll
        for (int ks = 0; ks < 2; ++ks) {
            bf16x8 tb;
#pragma unroll
            for (int j = 0; j < 8; ++j) {
                const int k = ks * 32 + 8 * g + j;
                tb[j] = (short)f2bf(W2b[k * 32 + o]);
            }
            wb[nt][ks] = tb;
        }
        bias2s[nt] = b2b[o];
    }

    unsigned short* const inrow = In + (wv * 16) * 128;
    unsigned short* const hrow0 = H + (wv * 16) * 64;

    const int ntile = (N + 15) >> 4;
    const int wid   = blockIdx.x * 4 + wv;
    const int nw    = gridDim.x * 4;

    for (int t = wid; t < ntile; t += nw) {
        const int nbase = t << 4;

        // ---- stage 16 nodes: 4 lanes/node, 32-float segment each ----
        // row layout (128 bf16): [x(32) | agg(32) | agg(32) | u(16)+0(16)]
        {
            const int le = lane >> 2;
            const int p  = lane & 3;
            const int n  = nbase + le;
            float4 v[8];
            if (n < N) {
                if (p == 0) {
                    const float4* xp = (const float4*)(x + (size_t)n * 32);
#pragma unroll
                    for (int q = 0; q < 8; ++q) v[q] = xp[q];
                } else if (p < 3) {
                    const int cnt = rowstart[n + 1] - rowstart[n];
                    const float inv = 1.0f / fmaxf((float)cnt, 1.0f);
                    const float4* sp = (const float4*)(summed + (size_t)n * 64 + (p - 1) * 32);
#pragma unroll
                    for (int q = 0; q < 8; ++q) {
                        v[q] = sp[q];
                        v[q].x *= inv; v[q].y *= inv; v[q].z *= inv; v[q].w *= inv;
                    }
                } else {
                    const int gb = batch[n];
                    const float4* up = (const float4*)(u + (size_t)gb * 16);
#pragma unroll
                    for (int q = 0; q < 4; ++q) v[q] = up[q];
#pragma unroll
                    for (int q = 4; q < 8; ++q) v[q] = float4{0.f, 0.f, 0.f, 0.f};
                }
            } else {
#pragma unroll
                for (int q = 0; q < 8; ++q) v[q] = float4{0.f, 0.f, 0.f, 0.f};
            }
            const int sw = le & 7;
            unsigned short* row = inrow + le * 128;
#pragma unroll
            for (int q = 0; q < 4; ++q) {
                bf16x8 c;
                const float4 va = v[2 * q], vb = v[2 * q + 1];
                c[0] = (short)f2bf(va.x); c[1] = (short)f2bf(va.y);
                c[2] = (short)f2bf(va.z); c[3] = (short)f2bf(va.w);
                c[4] = (short)f2bf(vb.x); c[5] = (short)f2bf(vb.y);
                c[6] = (short)f2bf(vb.z); c[7] = (short)f2bf(vb.w);
                const int cc = 4 * p + q;
                const int ci = (cc & 8) | ((cc & 7) ^ sw);
                *(bf16x8*)(row + ci * 8) = c;
            }
        }

        // ---- layer 1: 16 MFMAs over K=128 ----
        const unsigned short* brow = inrow + el * 128;
        const int sw7 = el & 7;
        f32x4 a0 = bias1[0], a1 = bias1[1], a2 = bias1[2], a3 = bias1[3];
#pragma unroll
        for (int ks = 0; ks < 4; ++ks) {
            const int cc = ks * 4 + g;
            const int ci = (cc & 8) | ((cc & 7) ^ sw7);
            const bf16x8 bf = *(const bf16x8*)(brow + ci * 8);
            a0 = __builtin_amdgcn_mfma_f32_16x16x32_bf16(wa[0][ks], bf, a0, 0, 0, 0);
            a1 = __builtin_amdgcn_mfma_f32_16x16x32_bf16(wa[1][ks], bf, a1, 0, 0, 0);
            a2 = __builtin_amdgcn_mfma_f32_16x16x32_bf16(wa[2][ks], bf, a2, 0, 0, 0);
            a3 = __builtin_amdgcn_mfma_f32_16x16x32_bf16(wa[3][ks], bf, a3, 0, 0, 0);
        }

        // ---- relu -> bf16 -> H (swizzled by el&7) ----
        unsigned short* hrow = hrow0 + el * 64;
        {
            f32x4 accs[4] = {a0, a1, a2, a3};
#pragma unroll
            for (int mt = 0; mt < 4; ++mt) {
                unsigned short pk[4];
#pragma unroll
                for (int r = 0; r < 4; ++r) pk[r] = f2bf(fmaxf(accs[mt][r], 0.f));
                const int hid   = mt * 16 + 4 * g;
                const int chunk = hid >> 3;
                const int off   = hid & 7;
                *(uint2*)(hrow + ((chunk ^ sw7) * 8 + off)) = *(uint2*)pk;
            }
        }

        // ---- layer 2 operand-swapped: D = H (A) x W2b (B) -> node-major ----
        const bf16x8 hb0 = *(const bf16x8*)(hrow + (((0 + g) ^ sw7) * 8));
        const bf16x8 hb1 = *(const bf16x8*)(hrow + (((4 + g) ^ sw7) * 8));
        f32x4 dn0 = {bias2s[0], bias2s[0], bias2s[0], bias2s[0]};
        f32x4 dn1 = {bias2s[1], bias2s[1], bias2s[1], bias2s[1]};
        dn0 = __builtin_amdgcn_mfma_f32_16x16x32_bf16(hb0, wb[0][0], dn0, 0, 0, 0);
        dn1 = __builtin_amdgcn_mfma_f32_16x16x32_bf16(hb0, wb[1][0], dn1, 0, 0, 0);
        dn0 = __builtin_amdgcn_mfma_f32_16x16x32_bf16(hb1, wb[0][1], dn0, 0, 0, 0);
        dn1 = __builtin_amdgcn_mfma_f32_16x16x32_bf16(hb1, wb[1][1], dn1, 0, 0, 0);

        // ---- store: lane holds node 4g+r, out nt*16+el ----
        if (nbase + 16 <= N) {
#pragma unroll
            for (int r = 0; r < 4; ++r) {
                float* dst = out + (size_t)(nbase + 4 * g + r) * 32 + el;
                dst[0]  = dn0[r];
                dst[16] = dn1[r];
            }
        } else {
#pragma unroll
            for (int r = 0; r < 4; ++r) {
                const int n = nbase + 4 * g + r;
                if (n < N) {
                    float* dst = out + (size_t)n * 32 + el;
                    dst[0]  = dn0[r];
                    dst[16] = dn1[r];
                }
            }
        }
    }
}

extern "C" void kernel_launch(void* const* d_in, const int* in_sizes, int n_in,
                              void* d_out, int out_size, void* d_ws, size_t ws_size,
                              hipStream_t stream) {
    const float* x     = (const float*)d_in[0];
    const int*   eidx  = (const int*)d_in[1];   // [2,E] int32
    const float* eattr = (const float*)d_in[2];
    const float* u     = (const float*)d_in[3];
    const int*   batch = (const int*)d_in[4];
    const float* W1a   = (const float*)d_in[5];
    const float* b1a   = (const float*)d_in[6];
    const float* W1b   = (const float*)d_in[7];
    const float* b1b   = (const float*)d_in[8];
    const float* W2a   = (const float*)d_in[9];
    const float* b2a   = (const float*)d_in[10];
    const float* W2b   = (const float*)d_in[11];
    const float* b2b   = (const float*)d_in[12];
    float* out = (float*)d_out;

    const int N = in_sizes[0] / 32;
    const int E = in_sizes[1] / 2;
    const int* erow = eidx;
    const int* ecol = eidx + E;

    // ws: sorted4[E] | summed[N*64] f32 | counts[N] | rowstart[N+1] | cursor[N] | bsum[256]
    int4*  sorted4  = (int4*)d_ws;
    float* summed   = (float*)(sorted4 + E);
    int*   counts   = (int*)(summed + (size_t)N * 64);
    int*   rowstart = counts + N;
    int*   cursor   = rowstart + (N + 1);
    int*   bsum     = cursor + N;

    // zero summed + counts (contiguous)
    hipMemsetAsync(summed, 0, ((size_t)N * 64 + N) * sizeof(float), stream);

    count_rows<<<1024, 256, 0, stream>>>(erow, counts, E);
    const int nb = (N + 255) / 256;
    scan_blocks<<<nb, 256, 0, stream>>>(counts, rowstart, bsum, N);
    scan_bsum<<<1, 256, 0, stream>>>(bsum, nb);
    scan_add<<<nb, 256, 0, stream>>>(rowstart, bsum, N, E);
    hipMemcpyAsync(cursor, rowstart, (size_t)N * sizeof(int),
                   hipMemcpyDeviceToDevice, stream);
    permute_edges<<<1024, 256, 0, stream>>>(erow, ecol, cursor, sorted4, E);

    edge_mlp_mfma<<<4096, 256, 0, stream>>>(x, sorted4, eattr,
                                            W1a, b1a, W1b, b1b, summed, E);
    node_mlp_mfma<<<784, 256, 0, stream>>>(x, summed, rowstart, u, batch,
                                           W2a, b2a, W2b, b2b, out, N);
}

// Round 11
// 334.997 us; speedup vs baseline: 1.4957x; 1.1458x over previous
//
#include <hip/hip_runtime.h>
#include <hip/hip_bf16.h>

// NodeModel: edge MLP ([x[col]||edge_attr] -> 64 relu -> 64 relu) -> scatter_mean
// over row -> node MLP ([x||agg||u[batch]] -> 64 relu -> 32).
// N=50000, E=1.6M, D_H=64.
//
// R11: shorten the per-tile serial chain (R6/R8-R10 showed occupancy/ILP can't
// be bought; the chain itself must shrink):
//  - gather loads land DIRECTLY in MFMA B-fragments (lane (g,el) reads
//    x[col(el)][8g..8g+8) + eattr[eid(el)][8g..8g+8), 2x32B) -> In LDS gone.
//  - segmented flush in REGISTERS: ballot-derived run mask (wave-uniform),
//    per run: predicated r-sum + shfl_xor g-reduce + ONE 256B coalesced
//    atomic -> D2 LDS + 16-step serial shfl/ds_read scan gone (~1100 cyc).
//  - only the H2 (layer1->layer2) LDS bounce remains. LDS 33KB -> 8KB/block.
// Occupancy point: (256,3), ~140 VGPR, no spill (R8/R9 lesson).

typedef __attribute__((ext_vector_type(8))) short bf16x8;
typedef __attribute__((ext_vector_type(4))) float f32x4;

__device__ __forceinline__ unsigned short f2bf(float f) {
    union { float f; unsigned u; } v; v.f = f;
    return (unsigned short)((v.u + 0x7FFFu + ((v.u >> 16) & 1u)) >> 16);
}

// ---------------- counting sort ----------------

__global__ __launch_bounds__(256) void count_rows(
    const int* __restrict__ erow, int* __restrict__ counts, int E)
{
    const int gid = blockIdx.x * blockDim.x + threadIdx.x;
    const int stride = gridDim.x * blockDim.x;
    const int n4 = E >> 2;
    for (int i = gid; i < n4; i += stride) {
        const int4 r = ((const int4*)erow)[i];
        atomicAdd(&counts[r.x], 1);
        atomicAdd(&counts[r.y], 1);
        atomicAdd(&counts[r.z], 1);
        atomicAdd(&counts[r.w], 1);
    }
    for (int i = (n4 << 2) + gid; i < E; i += stride)
        atomicAdd(&counts[erow[i]], 1);
}

__global__ __launch_bounds__(256) void scan_blocks(
    const int* __restrict__ counts, int* __restrict__ excl,
    int* __restrict__ bsum, int N)
{
    __shared__ int tmp[256];
    const int t = threadIdx.x;
    const int i = blockIdx.x * 256 + t;
    const int v = (i < N) ? counts[i] : 0;
    tmp[t] = v; __syncthreads();
#pragma unroll
    for (int o = 1; o < 256; o <<= 1) {
        const int a = (t >= o) ? tmp[t - o] : 0;
        __syncthreads();
        tmp[t] += a;
        __syncthreads();
    }
    if (i < N) excl[i] = tmp[t] - v;
    if (t == 255) bsum[blockIdx.x] = tmp[t];
}

__global__ __launch_bounds__(256) void scan_bsum(int* __restrict__ bsum, int nb)
{
    __shared__ int tmp[256];
    const int t = threadIdx.x;
    const int v = (t < nb) ? bsum[t] : 0;
    tmp[t] = v; __syncthreads();
#pragma unroll
    for (int o = 1; o < 256; o <<= 1) {
        const int a = (t >= o) ? tmp[t - o] : 0;
        __syncthreads();
        tmp[t] += a;
        __syncthreads();
    }
    if (t < nb) bsum[t] = tmp[t] - v;   // exclusive
}

__global__ __launch_bounds__(256) void scan_add(
    int* __restrict__ rowstart, const int* __restrict__ bsum, int N, int E)
{
    const int i = blockIdx.x * 256 + threadIdx.x;
    if (i < N) rowstart[i] += bsum[blockIdx.x];
    if (i == 0) rowstart[N] = E;
}

// sorted4[pos] = {edge_id, col, row, 0}
__global__ __launch_bounds__(256) void permute_edges(
    const int* __restrict__ erow, const int* __restrict__ ecol,
    int* __restrict__ cursor, int4* __restrict__ sorted4, int E)
{
    const int gid = blockIdx.x * blockDim.x + threadIdx.x;
    const int stride = gridDim.x * blockDim.x;
    const int n4 = E >> 2;
    for (int i = gid; i < n4; i += stride) {
        const int4 r = ((const int4*)erow)[i];
        const int4 c = ((const int4*)ecol)[i];
        const int e0 = i << 2;
        int pos;
        pos = atomicAdd(&cursor[r.x], 1); sorted4[pos] = int4{e0,     c.x, r.x, 0};
        pos = atomicAdd(&cursor[r.y], 1); sorted4[pos] = int4{e0 + 1, c.y, r.y, 0};
        pos = atomicAdd(&cursor[r.z], 1); sorted4[pos] = int4{e0 + 2, c.z, r.z, 0};
        pos = atomicAdd(&cursor[r.w], 1); sorted4[pos] = int4{e0 + 3, c.w, r.w, 0};
    }
    for (int i = (n4 << 2) + gid; i < E; i += stride) {
        const int r = erow[i];
        const int pos = atomicAdd(&cursor[r], 1);
        sorted4[pos] = int4{i, ecol[i], r, 0};
    }
}

// ---------------- edge MLP (sorted, register-resident) ----------------

__global__ __launch_bounds__(256, 3) void edge_mlp_mfma(
    const float* __restrict__ x,        // [N,32]
    const int4*  __restrict__ sorted4,  // [E] {eid,col,row,0}
    const float* __restrict__ eattr,    // [E,32]
    const float* __restrict__ W1a,      // [64,64] (in,out)
    const float* __restrict__ b1a,      // [64]
    const float* __restrict__ W1b,      // [64,64]
    const float* __restrict__ b1b,      // [64]
    float* __restrict__ summed,         // [N,64]
    int E)
{
    // Only remaining LDS: H2 bounce, [16 edges][64 hid] bf16 per wave (2KB).
    __shared__ __align__(16) unsigned short H2[4 * 16 * 64];

    const int tid  = threadIdx.x;
    const int lane = tid & 63;
    const int wv   = tid >> 6;
    const int g    = lane >> 4;
    const int el   = lane & 15;

    unsigned short* const h2w = H2 + wv * (16 * 64);

    // persistent weight fragments: A row = lane&15, k = 8*(lane>>4)+j;
    // B col = lane&15, same k (identical mappings)
    bf16x8 wa[4][2], wb[4][2];
    f32x4  bias1[4];
    float  bias2s[4];
#pragma unroll
    for (int mt = 0; mt < 4; ++mt) {
        const int o = mt * 16 + el;
#pragma unroll
        for (int ks = 0; ks < 2; ++ks) {
            bf16x8 ta, tb;
#pragma unroll
            for (int j = 0; j < 8; ++j) {
                const int k = ks * 32 + 8 * g + j;
                ta[j] = (short)f2bf(W1a[k * 64 + o]);
                tb[j] = (short)f2bf(W1b[k * 64 + o]);
            }
            wa[mt][ks] = ta;
            wb[mt][ks] = tb;
        }
#pragma unroll
        for (int r = 0; r < 4; ++r) bias1[mt][r] = b1a[mt * 16 + 4 * g + r];
        bias2s[mt] = b1b[o];
    }

    const int ntile = (E + 15) >> 4;
    const int wid   = blockIdx.x * 4 + wv;
    const int nw    = gridDim.x * 4;

    const int sw = el & 7;   // H2 swizzle

    for (int t = wid; t < ntile; t += nw) {
        const int ebase = t << 4;

        // ---- meta: lane (g,el) gets sorted4 of edge el (broadcast read) ----
        int4 s4;
        if (ebase + el < E) s4 = sorted4[ebase + el];
        else                s4 = int4{0, 0, -1, 0};
        const int row = s4.z;

        // ---- gather DIRECTLY into B-fragments: 2x32B per lane ----
        // layer-1 B: col=el(edge), k=8g+j; ks0 -> x feature 8g+j,
        //                                   ks1 -> eattr feature 8g+j.
        bf16x8 bf0, bf1;
        {
            const float4* xp = (const float4*)(x + (size_t)s4.y * 32 + 8 * g);
            const float4* ap = (const float4*)(eattr + (size_t)s4.x * 32 + 8 * g);
            const float4 x0 = xp[0], x1 = xp[1];
            const float4 a0v = ap[0], a1v = ap[1];
            bf0[0] = (short)f2bf(x0.x); bf0[1] = (short)f2bf(x0.y);
            bf0[2] = (short)f2bf(x0.z); bf0[3] = (short)f2bf(x0.w);
            bf0[4] = (short)f2bf(x1.x); bf0[5] = (short)f2bf(x1.y);
            bf0[6] = (short)f2bf(x1.z); bf0[7] = (short)f2bf(x1.w);
            bf1[0] = (short)f2bf(a0v.x); bf1[1] = (short)f2bf(a0v.y);
            bf1[2] = (short)f2bf(a0v.z); bf1[3] = (short)f2bf(a0v.w);
            bf1[4] = (short)f2bf(a1v.x); bf1[5] = (short)f2bf(a1v.y);
            bf1[6] = (short)f2bf(a1v.z); bf1[7] = (short)f2bf(a1v.w);
        }

        // ---- layer 1: D1 = W1a^T (A) x In^T (B) -> neuron-major ----
        f32x4 a0 = bias1[0], a1 = bias1[1], a2 = bias1[2], a3 = bias1[3];
        a0 = __builtin_amdgcn_mfma_f32_16x16x32_bf16(wa[0][0], bf0, a0, 0, 0, 0);
        a1 = __builtin_amdgcn_mfma_f32_16x16x32_bf16(wa[1][0], bf0, a1, 0, 0, 0);
        a2 = __builtin_amdgcn_mfma_f32_16x16x32_bf16(wa[2][0], bf0, a2, 0, 0, 0);
        a3 = __builtin_amdgcn_mfma_f32_16x16x32_bf16(wa[3][0], bf0, a3, 0, 0, 0);
        a0 = __builtin_amdgcn_mfma_f32_16x16x32_bf16(wa[0][1], bf1, a0, 0, 0, 0);
        a1 = __builtin_amdgcn_mfma_f32_16x16x32_bf16(wa[1][1], bf1, a1, 0, 0, 0);
        a2 = __builtin_amdgcn_mfma_f32_16x16x32_bf16(wa[2][1], bf1, a2, 0, 0, 0);
        a3 = __builtin_amdgcn_mfma_f32_16x16x32_bf16(wa[3][1], bf1, a3, 0, 0, 0);

        // ---- relu -> bf16 -> H2 (wave-private, swizzled) ----
        unsigned short* hrow = h2w + el * 64;
        {
            f32x4 accs[4] = {a0, a1, a2, a3};
#pragma unroll
            for (int mt = 0; mt < 4; ++mt) {
                unsigned short pk[4];
#pragma unroll
                for (int r = 0; r < 4; ++r) pk[r] = f2bf(fmaxf(accs[mt][r], 0.f));
                const int hid   = mt * 16 + 4 * g;
                const int chunk = hid >> 3;
                const int off   = hid & 7;
                *(uint2*)(hrow + ((chunk ^ sw) * 8 + off)) = *(uint2*)pk;
            }
        }

        // ---- layer 2, operand-swapped: D2 = H1 (A) x W1b (B) -> EDGE-major ----
        const bf16x8 hb0 = *(const bf16x8*)(hrow + (((0 + g) ^ sw) * 8));
        const bf16x8 hb1 = *(const bf16x8*)(hrow + (((4 + g) ^ sw) * 8));
        f32x4 d0 = {bias2s[0], bias2s[0], bias2s[0], bias2s[0]};
        f32x4 d1 = {bias2s[1], bias2s[1], bias2s[1], bias2s[1]};
        f32x4 d2 = {bias2s[2], bias2s[2], bias2s[2], bias2s[2]};
        f32x4 d3 = {bias2s[3], bias2s[3], bias2s[3], bias2s[3]};
        d0 = __builtin_amdgcn_mfma_f32_16x16x32_bf16(hb0, wb[0][0], d0, 0, 0, 0);
        d1 = __builtin_amdgcn_mfma_f32_16x16x32_bf16(hb0, wb[1][0], d1, 0, 0, 0);
        d2 = __builtin_amdgcn_mfma_f32_16x16x32_bf16(hb0, wb[2][0], d2, 0, 0, 0);
        d3 = __builtin_amdgcn_mfma_f32_16x16x32_bf16(hb0, wb[3][0], d3, 0, 0, 0);
        d0 = __builtin_amdgcn_mfma_f32_16x16x32_bf16(hb1, wb[0][1], d0, 0, 0, 0);
        d1 = __builtin_amdgcn_mfma_f32_16x16x32_bf16(hb1, wb[1][1], d1, 0, 0, 0);
        d2 = __builtin_amdgcn_mfma_f32_16x16x32_bf16(hb1, wb[2][1], d2, 0, 0, 0);
        d3 = __builtin_amdgcn_mfma_f32_16x16x32_bf16(hb1, wb[3][1], d3, 0, 0, 0);

        // ---- relu in registers (per edge-output) ----
#pragma unroll
        for (int r = 0; r < 4; ++r) {
            d0[r] = fmaxf(d0[r], 0.f);
            d1[r] = fmaxf(d1[r], 0.f);
            d2[r] = fmaxf(d2[r], 0.f);
            d3[r] = fmaxf(d3[r], 0.f);
        }

        // ---- register-space segmented flush ----
        // run boundaries from ballot (wave-uniform); per run: predicated r-sum,
        // shfl_xor g-reduce, one 256B coalesced atomic.
        const int prevrow = __shfl(row, lane - 1);   // valid for g==0 && el>0
        unsigned long long bmask =
            __ballot((g == 0) && (el > 0) && (row != prevrow));
        bmask = (bmask & 0xFFFEull) | 0x10000ull;    // bits 1..15 + sentinel@16

        int s = 0;
        while (s < 16) {
            const int e = s + 1 + (__ffsll(bmask >> (s + 1)) - 1);
            const int rowid = __shfl(row, s);
            if (rowid >= 0) {
                float s0 = 0.f, s1 = 0.f, s2 = 0.f, s3 = 0.f;
#pragma unroll
                for (int r = 0; r < 4; ++r) {
                    const int ej = 4 * g + r;
                    const bool in = (ej >= s) && (ej < e);
                    s0 += in ? d0[r] : 0.f;
                    s1 += in ? d1[r] : 0.f;
                    s2 += in ? d2[r] : 0.f;
                    s3 += in ? d3[r] : 0.f;
                }
                s0 += __shfl_xor(s0, 16); s0 += __shfl_xor(s0, 32);
                s1 += __shfl_xor(s1, 16); s1 += __shfl_xor(s1, 32);
                s2 += __shfl_xor(s2, 16); s2 += __shfl_xor(s2, 32);
                s3 += __shfl_xor(s3, 16); s3 += __shfl_xor(s3, 32);
                const float val = (g == 0) ? s0 : (g == 1) ? s1
                                : (g == 2) ? s2 : s3;
                unsafeAtomicAdd(&summed[(size_t)rowid * 64 + lane], val);
            }
            s = e;
        }
    }
}

// ---------------- node MLP via MFMA ----------------

__global__ __launch_bounds__(256, 2) void node_mlp_mfma(
    const float* __restrict__ x,        // [N,32]
    const float* __restrict__ summed,   // [N,64]
    const int*   __restrict__ rowstart, // [N+1]
    const float* __restrict__ u,        // [G,16]
    const int*   __restrict__ batch,    // [N]
    const float* __restrict__ W2a,      // [112,64]
    const float* __restrict__ b2a,      // [64]
    const float* __restrict__ W2b,      // [64,32]
    const float* __restrict__ b2b,      // [32]
    float* __restrict__ out,            // [N,32]
    int N)
{
    __shared__ __align__(16) unsigned short In[64 * 128];  // 16KB
    __shared__ __align__(16) unsigned short H[64 * 64];    // 8KB

    const int tid  = threadIdx.x;
    const int lane = tid & 63;
    const int wv   = tid >> 6;
    const int g    = lane >> 4;
    const int el   = lane & 15;

    bf16x8 wa[4][4];
    f32x4  bias1[4];
#pragma unroll
    for (int mt = 0; mt < 4; ++mt) {
        const int o = mt * 16 + el;
#pragma unroll
        for (int ks = 0; ks < 4; ++ks) {
            bf16x8 ta;
#pragma unroll
            for (int j = 0; j < 8; ++j) {
                const int k = ks * 32 + 8 * g + j;
                ta[j] = (k < 112) ? (short)f2bf(W2a[k * 64 + o]) : (short)0;
            }
            wa[mt][ks] = ta;
        }
#pragma unroll
        for (int r = 0; r < 4; ++r) bias1[mt][r] = b2a[mt * 16 + 4 * g + r];
    }
    bf16x8 wb[2][2];
    float  bias2s[2];
#pragma unroll
    for (int nt = 0; nt < 2; ++nt) {
        const int o = nt * 16 + el;
#pragma unroll
        for (int ks = 0; ks < 2; ++ks) {
            bf16x8 tb;
#pragma unroll
            for (int j = 0; j < 8; ++j) {
                const int k = ks * 32 + 8 * g + j;
                tb[j] = (short)f2bf(W2b[k * 32 + o]);
            }
            wb[nt][ks] = tb;
        }
        bias2s[nt] = b2b[o];
    }

    unsigned short* const inrow = In + (wv * 16) * 128;
    unsigned short* const hrow0 = H + (wv * 16) * 64;

    const int ntile = (N + 15) >> 4;
    const int wid   = blockIdx.x * 4 + wv;
    const int nw    = gridDim.x * 4;

    for (int t = wid; t < ntile; t += nw) {
        const int nbase = t << 4;

        // ---- stage 16 nodes: 4 lanes/node, 32-float segment each ----
        // row layout (128 bf16): [x(32) | agg(32) | agg(32) | u(16)+0(16)]
        {
            const int le = lane >> 2;
            const int p  = lane & 3;
            const int n  = nbase + le;
            float4 v[8];
            if (n < N) {
                if (p == 0) {
                    const float4* xp = (const float4*)(x + (size_t)n * 32);
#pragma unroll
                    for (int q = 0; q < 8; ++q) v[q] = xp[q];
                } else if (p < 3) {
                    const int cnt = rowstart[n + 1] - rowstart[n];
                    const float inv = 1.0f / fmaxf((float)cnt, 1.0f);
                    const float4* sp = (const float4*)(summed + (size_t)n * 64 + (p - 1) * 32);
#pragma unroll
                    for (int q = 0; q < 8; ++q) {
                        v[q] = sp[q];
                        v[q].x *= inv; v[q].y *= inv; v[q].z *= inv; v[q].w *= inv;
                    }
                } else {
                    const int gb = batch[n];
                    const float4* up = (const float4*)(u + (size_t)gb * 16);
#pragma unroll
                    for (int q = 0; q < 4; ++q) v[q] = up[q];
#pragma unroll
                    for (int q = 4; q < 8; ++q) v[q] = float4{0.f, 0.f, 0.f, 0.f};
                }
            } else {
#pragma unroll
                for (int q = 0; q < 8; ++q) v[q] = float4{0.f, 0.f, 0.f, 0.f};
            }
            const int sw = le & 7;
            unsigned short* row = inrow + le * 128;
#pragma unroll
            for (int q = 0; q < 4; ++q) {
                bf16x8 c;
                const float4 va = v[2 * q], vb = v[2 * q + 1];
                c[0] = (short)f2bf(va.x); c[1] = (short)f2bf(va.y);
                c[2] = (short)f2bf(va.z); c[3] = (short)f2bf(va.w);
                c[4] = (short)f2bf(vb.x); c[5] = (short)f2bf(vb.y);
                c[6] = (short)f2bf(vb.z); c[7] = (short)f2bf(vb.w);
                const int cc = 4 * p + q;
                const int ci = (cc & 8) | ((cc & 7) ^ sw);
                *(bf16x8*)(row + ci * 8) = c;
            }
        }

        // ---- layer 1: 16 MFMAs over K=128 ----
        const unsigned short* brow = inrow + el * 128;
        const int sw7 = el & 7;
        f32x4 a0 = bias1[0], a1 = bias1[1], a2 = bias1[2], a3 = bias1[3];
#pragma unroll
        for (int ks = 0; ks < 4; ++ks) {
            const int cc = ks * 4 + g;
            const int ci = (cc & 8) | ((cc & 7) ^ sw7);
            const bf16x8 bf = *(const bf16x8*)(brow + ci * 8);
            a0 = __builtin_amdgcn_mfma_f32_16x16x32_bf16(wa[0][ks], bf, a0, 0, 0, 0);
            a1 = __builtin_amdgcn_mfma_f32_16x16x32_bf16(wa[1][ks], bf, a1, 0, 0, 0);
            a2 = __builtin_amdgcn_mfma_f32_16x16x32_bf16(wa[2][ks], bf, a2, 0, 0, 0);
            a3 = __builtin_amdgcn_mfma_f32_16x16x32_bf16(wa[3][ks], bf, a3, 0, 0, 0);
        }

        // ---- relu -> bf16 -> H (swizzled by el&7) ----
        unsigned short* hrow = hrow0 + el * 64;
        {
            f32x4 accs[4] = {a0, a1, a2, a3};
#pragma unroll
            for (int mt = 0; mt < 4; ++mt) {
                unsigned short pk[4];
#pragma unroll
                for (int r = 0; r < 4; ++r) pk[r] = f2bf(fmaxf(accs[mt][r], 0.f));
                const int hid   = mt * 16 + 4 * g;
                const int chunk = hid >> 3;
                const int off   = hid & 7;
                *(uint2*)(hrow + ((chunk ^ sw7) * 8 + off)) = *(uint2*)pk;
            }
        }

        // ---- layer 2 operand-swapped: D = H (A) x W2b (B) -> node-major ----
        const bf16x8 hb0 = *(const bf16x8*)(hrow + (((0 + g) ^ sw7) * 8));
        const bf16x8 hb1 = *(const bf16x8*)(hrow + (((4 + g) ^ sw7) * 8));
        f32x4 dn0 = {bias2s[0], bias2s[0], bias2s[0], bias2s[0]};
        f32x4 dn1 = {bias2s[1], bias2s[1], bias2s[1], bias2s[1]};
        dn0 = __builtin_amdgcn_mfma_f32_16x16x32_bf16(hb0, wb[0][0], dn0, 0, 0, 0);
        dn1 = __builtin_amdgcn_mfma_f32_16x16x32_bf16(hb0, wb[1][0], dn1, 0, 0, 0);
        dn0 = __builtin_amdgcn_mfma_f32_16x16x32_bf16(hb1, wb[0][1], dn0, 0, 0, 0);
        dn1 = __builtin_amdgcn_mfma_f32_16x16x32_bf16(hb1, wb[1][1], dn1, 0, 0, 0);

        // ---- store: lane holds node 4g+r, out nt*16+el ----
        if (nbase + 16 <= N) {
#pragma unroll
            for (int r = 0; r < 4; ++r) {
                float* dst = out + (size_t)(nbase + 4 * g + r) * 32 + el;
                dst[0]  = dn0[r];
                dst[16] = dn1[r];
            }
        } else {
#pragma unroll
            for (int r = 0; r < 4; ++r) {
                const int n = nbase + 4 * g + r;
                if (n < N) {
                    float* dst = out + (size_t)n * 32 + el;
                    dst[0]  = dn0[r];
                    dst[16] = dn1[r];
                }
            }
        }
    }
}

extern "C" void kernel_launch(void* const* d_in, const int* in_sizes, int n_in,
                              void* d_out, int out_size, void* d_ws, size_t ws_size,
                              hipStream_t stream) {
    const float* x     = (const float*)d_in[0];
    const int*   eidx  = (const int*)d_in[1];   // [2,E] int32
    const float* eattr = (const float*)d_in[2];
    const float* u     = (const float*)d_in[3];
    const int*   batch = (const int*)d_in[4];
    const float* W1a   = (const float*)d_in[5];
    const float* b1a   = (const float*)d_in[6];
    const float* W1b   = (const float*)d_in[7];
    const float* b1b   = (const float*)d_in[8];
    const float* W2a   = (const float*)d_in[9];
    const float* b2a   = (const float*)d_in[10];
    const float* W2b   = (const float*)d_in[11];
    const float* b2b   = (const float*)d_in[12];
    float* out = (float*)d_out;

    const int N = in_sizes[0] / 32;
    const int E = in_sizes[1] / 2;
    const int* erow = eidx;
    const int* ecol = eidx + E;

    // ws: sorted4[E] | summed[N*64] f32 | counts[N] | rowstart[N+1] | cursor[N] | bsum[256]
    int4*  sorted4  = (int4*)d_ws;
    float* summed   = (float*)(sorted4 + E);
    int*   counts   = (int*)(summed + (size_t)N * 64);
    int*   rowstart = counts + N;
    int*   cursor   = rowstart + (N + 1);
    int*   bsum     = cursor + N;

    // zero summed + counts (contiguous)
    hipMemsetAsync(summed, 0, ((size_t)N * 64 + N) * sizeof(float), stream);

    count_rows<<<1024, 256, 0, stream>>>(erow, counts, E);
    const int nb = (N + 255) / 256;
    scan_blocks<<<nb, 256, 0, stream>>>(counts, rowstart, bsum, N);
    scan_bsum<<<1, 256, 0, stream>>>(bsum, nb);
    scan_add<<<nb, 256, 0, stream>>>(rowstart, bsum, N, E);
    hipMemcpyAsync(cursor, rowstart, (size_t)N * sizeof(int),
                   hipMemcpyDeviceToDevice, stream);
    permute_edges<<<1024, 256, 0, stream>>>(erow, ecol, cursor, sorted4, E);

    edge_mlp_mfma<<<4096, 256, 0, stream>>>(x, sorted4, eattr,
                                            W1a, b1a, W1b, b1b, summed, E);
    node_mlp_mfma<<<784, 256, 0, stream>>>(x, summed, rowstart, u, batch,
                                           W2a, b2a, W2b, b2b, out, N);
}